// Round 2
// baseline (218.849 us; speedup 1.0000x reference)
//
#include <hip/hip_runtime.h>
#include <hip/hip_bf16.h>

#define DP     257
#define NP     2049
#define NSEQ   2048
#define NB     16
#define KLD    288         // pitch for small matrices (shorts)
#define HROWS  320         // padded rows for Hb
#define TPITCH 320         // Hbt pitch in shorts: 640 B = 5 full 128B lines
#define TROWS  2176        // padded t rows for Hbt (17*128)
#define KPAD   40          // LDS row pitch (shorts) for gram_staged
#define KP2    36          // LDS row pitch (shorts) for attn_v4: 72 B = 18-bank stride
                           //  -> 16 frag rows hit 16 distinct banks (conflict-free)

typedef __attribute__((ext_vector_type(8))) short bf16x8;
typedef __attribute__((ext_vector_type(4))) short bf16x4;
typedef __attribute__((ext_vector_type(4))) float f32x4;

// ---------------------------------------------------------------------------
// Convert H -> Hb (row-major bf16, 320 x 2048, = masked H-hat)
//           -> Hbt (transposed bf16, 2176 x 320-pitch, zero-padded)
// ---------------------------------------------------------------------------
__global__ __launch_bounds__(256) void conv_h(const float* __restrict__ H,
                                              __hip_bfloat16* __restrict__ Hb,
                                              __hip_bfloat16* __restrict__ Hbt) {
    const int b  = blockIdx.z;
    const int t0 = blockIdx.x * 64;
    const int e0 = blockIdx.y * 64;
    const float* __restrict__ Hs = H + (size_t)b * DP * NP;
    __hip_bfloat16* __restrict__ Hbb  = Hb  + (size_t)b * HROWS * 2048;
    __hip_bfloat16* __restrict__ Hbtb = Hbt + (size_t)b * TROWS * TPITCH;

    __shared__ float tile[64][65];

    const int tl = threadIdx.x & 63;
    const int er = threadIdx.x >> 6;
#pragma unroll
    for (int r = 0; r < 16; ++r) {
        const int el = er + r * 4;        // 0..63
        const int ge = e0 + el;
        const int gt = t0 + tl;
        float v = 0.f;
        if (ge < DP && gt < NP) v = Hs[(size_t)ge * NP + gt];
        tile[el][tl] = v;
        if (ge < HROWS && gt < 2048) Hbb[(size_t)ge * 2048 + gt] = __float2bfloat16(v);
    }
    __syncthreads();
#pragma unroll
    for (int r = 0; r < 16; ++r) {
        const int ttl = er + r * 4;       // t-local
        const int gt = t0 + ttl;
        const int ge = e0 + tl;           // e-local = lane -> contiguous writes
        if (gt < TROWS && ge < TPITCH) {
            const float v = (ge < KLD) ? tile[tl][ttl] : 0.f;
            Hbtb[(size_t)gt * TPITCH + ge] = __float2bfloat16(v);
        }
    }
}

// ---------------------------------------------------------------------------
// Pb[m][k] = P[m][k] (bf16, zero-padded to 288x288); Qt[n][k] = Q[k][n]
// ---------------------------------------------------------------------------
__global__ __launch_bounds__(256) void conv_pq(const float* __restrict__ P,
                                               const float* __restrict__ Q,
                                               __hip_bfloat16* __restrict__ Pb,
                                               __hip_bfloat16* __restrict__ Qt) {
    const int c0 = blockIdx.x * 64;
    const int r0 = blockIdx.y * 64;
    const int tl = threadIdx.x & 63;
    const int rr = threadIdx.x >> 6;
    __shared__ float tile[64][65];

    if (blockIdx.z == 0) {
#pragma unroll
        for (int r = 0; r < 16; ++r) {
            const int m = r0 + rr + r * 4;
            const int k = c0 + tl;
            float v = (m < DP && k < DP) ? P[m * DP + k] : 0.f;
            if (m < KLD && k < KLD) Pb[m * KLD + k] = __float2bfloat16(v);
        }
    } else {
#pragma unroll
        for (int r = 0; r < 16; ++r) {
            const int k = r0 + rr + r * 4;
            const int n = c0 + tl;
            float v = (k < DP && n < DP) ? Q[k * DP + n] : 0.f;
            tile[k - r0][n - c0] = v;
        }
        __syncthreads();
#pragma unroll
        for (int r = 0; r < 16; ++r) {
            const int k = r0 + tl;
            const int n = c0 + rr + r * 4;
            if (n < KLD && k < KLD) Qt[n * KLD + k] = __float2bfloat16(tile[tl][n - c0]);
        }
    }
}

// ---------------------------------------------------------------------------
// G[b] = Hb[b] @ Hb[b]^T, staged 64x64 tiles, 512 threads, split-K x2.
// (unchanged)
// ---------------------------------------------------------------------------
__global__ __launch_bounds__(512, 4) void gram_staged(const __hip_bfloat16* __restrict__ Hb,
                                                      __hip_bfloat16* __restrict__ G) {
    const int b  = blockIdx.y;
    const int tm = blockIdx.x / 5;
    const int tn = blockIdx.x % 5;
    const int m0 = tm * 64, n0 = tn * 64;
    const int tid = threadIdx.x;
    const int wave = tid >> 6, lane = tid & 63;
    const int lrow = lane & 15, kq = (lane >> 4) * 8;
    const int hw = wave >> 2;            // compute half
    const int q  = wave & 3;             // quadrant
    const int mh = (q & 1) * 32, nh = (q >> 1) * 32;
    const int hs = tid >> 8;             // staging half
    const int t2 = tid & 255;
    const int sr = t2 >> 2;              // 0..63
    const int sc = (t2 & 3) * 8;         // 0,8,16,24

    __shared__ __align__(16) char smem[2 * 2 * 2 * 64 * KPAD * 2];  // 40960 B
    short* As = (short*)smem;                    // [buf][h][64][KPAD]
    short* Bs = (short*)(smem + 2 * 2 * 64 * KPAD * 2);
    float* red = (float*)smem;                   // [8][32][32] (reused after loop)

    const short* __restrict__ base = (const short*)(Hb + (size_t)b * HROWS * 2048);

    auto aoff = [&](int buf, int h, int r) { return ((buf * 2 + h) * 64 + r) * KPAD; };

    f32x4 acc[2][2] = {};

    {
        const int kb = hs * 1024;
        *(bf16x8*)&As[aoff(0, hs, sr) + sc] = *(const bf16x8*)(base + (size_t)(m0 + sr) * 2048 + kb + sc);
        *(bf16x8*)&Bs[aoff(0, hs, sr) + sc] = *(const bf16x8*)(base + (size_t)(n0 + sr) * 2048 + kb + sc);
    }
    __syncthreads();

    for (int kt = 0; kt < 32; ++kt) {
        const int cur = kt & 1, nxt = cur ^ 1;
        if (kt + 1 < 32) {
            const int kb = hs * 1024 + (kt + 1) * 32;
            *(bf16x8*)&As[aoff(nxt, hs, sr) + sc] = *(const bf16x8*)(base + (size_t)(m0 + sr) * 2048 + kb + sc);
            *(bf16x8*)&Bs[aoff(nxt, hs, sr) + sc] = *(const bf16x8*)(base + (size_t)(n0 + sr) * 2048 + kb + sc);
        }
        bf16x8 a0 = *(const bf16x8*)&As[aoff(cur, hw, mh + lrow) + kq];
        bf16x8 a1 = *(const bf16x8*)&As[aoff(cur, hw, mh + 16 + lrow) + kq];
        bf16x8 b0 = *(const bf16x8*)&Bs[aoff(cur, hw, nh + lrow) + kq];
        bf16x8 b1 = *(const bf16x8*)&Bs[aoff(cur, hw, nh + 16 + lrow) + kq];
        acc[0][0] = __builtin_amdgcn_mfma_f32_16x16x32_bf16(a0, b0, acc[0][0], 0, 0, 0);
        acc[0][1] = __builtin_amdgcn_mfma_f32_16x16x32_bf16(a0, b1, acc[0][1], 0, 0, 0);
        acc[1][0] = __builtin_amdgcn_mfma_f32_16x16x32_bf16(a1, b0, acc[1][0], 0, 0, 0);
        acc[1][1] = __builtin_amdgcn_mfma_f32_16x16x32_bf16(a1, b1, acc[1][1], 0, 0, 0);
        __syncthreads();
    }

    const int ccol  = lane & 15;
    const int crow0 = (lane >> 4) * 4;
#pragma unroll
    for (int i = 0; i < 2; ++i)
#pragma unroll
        for (int j = 0; j < 2; ++j)
#pragma unroll
            for (int r = 0; r < 4; ++r)
                red[((wave * 32) + i * 16 + crow0 + r) * 32 + j * 16 + ccol] = acc[i][j][r];
    __syncthreads();

    const int q2  = tid >> 7;
    const int t7  = tid & 127;
    const int row = t7 >> 2;
    const int c8  = (t7 & 3) * 8;
    const int gm = m0 + (q2 & 1) * 32 + row;
    const int gn = n0 + (q2 >> 1) * 32 + c8;
    if (gm < KLD && gn < KLD) {
        __hip_bfloat16 o[8];
#pragma unroll
        for (int t = 0; t < 8; ++t) {
            const float v = red[((q2 * 32) + row) * 32 + c8 + t] +
                            red[(((q2 + 4) * 32) + row) * 32 + c8 + t];
            o[t] = __float2bfloat16((gm < DP && (gn + t) < DP) ? v : 0.f);
        }
        __hip_bfloat16* __restrict__ Gb = G + (size_t)b * KLD * KLD;
        *(bf16x8*)&Gb[gm * KLD + gn] = *(const bf16x8*)o;
    }
}

// ---------------------------------------------------------------------------
// C[b][m][n] = sum_k A[m][k] * B[n][k]  (K=288, ld=288), split-K x4.
// (unchanged)
// ---------------------------------------------------------------------------
__global__ __launch_bounds__(256) void mm_sk4(const __hip_bfloat16* __restrict__ A,
                                              const __hip_bfloat16* __restrict__ B,
                                              __hip_bfloat16* __restrict__ C,
                                              int strideA, int strideB) {
    const int b  = blockIdx.y;
    const int tm = blockIdx.x / 9;
    const int tn = blockIdx.x % 9;
    const int s    = threadIdx.x >> 6;
    const int lane = threadIdx.x & 63;
    const int lrow = lane & 15;
    const int koff = (lane >> 4) * 8;
    const short* __restrict__ Ab = (const short*)(A + (size_t)b * strideA);
    const short* __restrict__ Bb = (const short*)(B + (size_t)b * strideB);
    const int m0 = tm * 32, n0 = tn * 32;

    __shared__ float red[4][32][32];

    f32x4 acc[2][2] = {};
    for (int kt = s; kt < 9; kt += 4) {
        const int k0 = kt * 32;
        bf16x8 a0 = *(const bf16x8*)(Ab + (m0 + lrow)      * KLD + k0 + koff);
        bf16x8 a1 = *(const bf16x8*)(Ab + (m0 + 16 + lrow) * KLD + k0 + koff);
        bf16x8 c0 = *(const bf16x8*)(Bb + (n0 + lrow)      * KLD + k0 + koff);
        bf16x8 c1 = *(const bf16x8*)(Bb + (n0 + 16 + lrow) * KLD + k0 + koff);
        acc[0][0] = __builtin_amdgcn_mfma_f32_16x16x32_bf16(a0, c0, acc[0][0], 0, 0, 0);
        acc[0][1] = __builtin_amdgcn_mfma_f32_16x16x32_bf16(a0, c1, acc[0][1], 0, 0, 0);
        acc[1][0] = __builtin_amdgcn_mfma_f32_16x16x32_bf16(a1, c0, acc[1][0], 0, 0, 0);
        acc[1][1] = __builtin_amdgcn_mfma_f32_16x16x32_bf16(a1, c1, acc[1][1], 0, 0, 0);
    }

    const int ccol  = lane & 15;
    const int crow0 = (lane >> 4) * 4;
#pragma unroll
    for (int i = 0; i < 2; ++i)
#pragma unroll
        for (int j = 0; j < 2; ++j)
#pragma unroll
            for (int r = 0; r < 4; ++r)
                red[s][i * 16 + crow0 + r][j * 16 + ccol] = acc[i][j][r];
    __syncthreads();

    const int row = threadIdx.x >> 3;
    const int c4  = (threadIdx.x & 7) * 4;
    float4 v0 = *(const float4*)&red[0][row][c4];
    float4 v1 = *(const float4*)&red[1][row][c4];
    float4 v2 = *(const float4*)&red[2][row][c4];
    float4 v3 = *(const float4*)&red[3][row][c4];
    float sum[4] = {v0.x + v1.x + v2.x + v3.x,
                    v0.y + v1.y + v2.y + v3.y,
                    v0.z + v1.z + v2.z + v3.z,
                    v0.w + v1.w + v2.w + v3.w};
    const int gm = m0 + row;
    const int gn = n0 + c4;
    __hip_bfloat16 o[4];
#pragma unroll
    for (int t = 0; t < 4; ++t) {
        const float v = (gm < DP && (gn + t) < DP) ? sum[t] : 0.f;
        o[t] = __float2bfloat16(v);
    }
    __hip_bfloat16* __restrict__ Cb = C + (size_t)b * KLD * KLD;
    *(bf16x4*)&Cb[gm * KLD + gn] = *(const bf16x4*)o;
}

// ---------------------------------------------------------------------------
// out[b][d][t] = H[b][d][t] + (1/n) * sum_e Kb[d][e] * Hbt[t][e]
//
// v4: back to LDS staging (v2 structure) but tuned for TLP, which the v2/v3
// counters showed is the real limiter (nothing saturated, occupancy <40%):
//  * 64d x 64t tile -> 2640 blocks = 10.3 blocks/CU (v2: 5.3)
//  * double-buffered LDS, ONE __syncthreads per K-chunk (v2 had two)
//  * KP2=36 pitch: 18-bank row stride -> conflict-free frag reads; 18.4 KB
//    LDS -> 8 blocks/CU by LDS
//  * bijective XCD swizzle (2640 % 8 == 0): each XCD owns 2 batches, the 5
//    d-blocks sharing an Hbt t-panel are consecutive on ONE XCD -> L2 reuse
// ---------------------------------------------------------------------------
__global__ __launch_bounds__(256, 7) void attn_v4(const __hip_bfloat16* __restrict__ Kb,
                                                  const __hip_bfloat16* __restrict__ Hbt,
                                                  const float* __restrict__ H,
                                                  float* __restrict__ Out) {
    // XCD-aware remap: hw id % 8 = XCD; give each XCD a contiguous logical range
    const int id      = blockIdx.x;            // 0..2639
    const int logical = (id & 7) * 330 + (id >> 3);
    const int y  = logical % 5;                // d-block
    const int xb = logical / 5;
    const int x  = xb % 33;                    // t-block
    const int b  = xb / 33;                    // batch (each XCD: 2 batches)

    const int d0 = y * 64;
    const int t0 = x * 64;
    const int tid = threadIdx.x;
    const int wave = tid >> 6, lane = tid & 63;
    const int lrow = lane & 15, kq = (lane >> 4) * 8;
    const int dh = (wave & 1) * 32;      // wave's d-half (32 rows)
    const int th = (wave >> 1) * 32;     // wave's t-half (32 cols)
    const int sr = tid >> 2;             // 0..63
    const int sc = (tid & 3) * 8;        // 0,8,16,24

    __shared__ __align__(16) char smem[2 * 128 * KP2 * 2];   // 18432 B
    short* buf = (short*)smem;           // [2][128][KP2]; rows 0..63 = A, 64..127 = B
    float* Ped = (float*)smem;           // [16][68] epilogue staging (reuse)

    const short* __restrict__ Ka = (const short*)(Kb  + (size_t)b * KLD * KLD);
    const short* __restrict__ Ta = (const short*)(Hbt + (size_t)b * TROWS * TPITCH);

    // A rows: clamp into the zero-padded tail (rows 257..287 of Kb are zeros)
    int rA = d0 + sr; if (rA > KLD - 1) rA = KLD - 1;
    const short* __restrict__ pA = Ka + (size_t)rA * KLD + sc;
    const short* __restrict__ pB = Ta + (size_t)(t0 + sr) * TPITCH + sc;

    auto boff = [](int bi, int r) { return (bi * 128 + r) * KP2; };

    // prologue: stage chunk 0
    {
        bf16x8 ra = *(const bf16x8*)pA;
        bf16x8 rb = *(const bf16x8*)pB;
        *(bf16x8*)&buf[boff(0, sr) + sc]      = ra;
        *(bf16x8*)&buf[boff(0, 64 + sr) + sc] = rb;
    }
    __syncthreads();

    f32x4 acc[2][2] = {};

    for (int kt = 0; kt < 9; ++kt) {
        const int cur = kt & 1;
        bf16x8 na, nb;
        if (kt < 8) {                         // issue next-chunk loads early
            const int e = (kt + 1) * 32;
            na = *(const bf16x8*)(pA + e);
            nb = *(const bf16x8*)(pB + e);
        }
        bf16x8 a0 = *(const bf16x8*)&buf[boff(cur, dh + lrow) + kq];
        bf16x8 a1 = *(const bf16x8*)&buf[boff(cur, dh + 16 + lrow) + kq];
        bf16x8 b0 = *(const bf16x8*)&buf[boff(cur, 64 + th + lrow) + kq];
        bf16x8 b1 = *(const bf16x8*)&buf[boff(cur, 64 + th + 16 + lrow) + kq];
        acc[0][0] = __builtin_amdgcn_mfma_f32_16x16x32_bf16(a0, b0, acc[0][0], 0, 0, 0);
        acc[0][1] = __builtin_amdgcn_mfma_f32_16x16x32_bf16(a0, b1, acc[0][1], 0, 0, 0);
        acc[1][0] = __builtin_amdgcn_mfma_f32_16x16x32_bf16(a1, b0, acc[1][0], 0, 0, 0);
        acc[1][1] = __builtin_amdgcn_mfma_f32_16x16x32_bf16(a1, b1, acc[1][1], 0, 0, 0);
        if (kt < 8) {                         // write next buffer (no conflict with cur)
            *(bf16x8*)&buf[boff(cur ^ 1, sr) + sc]      = na;
            *(bf16x8*)&buf[boff(cur ^ 1, 64 + sr) + sc] = nb;
        }
        __syncthreads();                      // ONE barrier per chunk
    }

    // epilogue: 4 chunks of 16 d-rows through LDS, lane-contiguous RMW
    const float* __restrict__ Hs = H + (size_t)b * DP * NP;
    float* __restrict__ Ob = Out + (size_t)b * DP * NP;
    const float inv_n = 1.0f / (float)NSEQ;
    const int ccol  = lane & 15;
    const int crow0 = (lane >> 4) * 4;
    const bool fullT = (t0 + 64 <= NP);       // false only for the x=32 block

#pragma unroll
    for (int c = 0; c < 4; ++c) {
        // waves whose d-half matches this chunk dump their i = (c&1) frags
        if ((wave & 1) == (c >> 1)) {
            const int i = c & 1;
#pragma unroll
            for (int j = 0; j < 2; ++j)
#pragma unroll
                for (int r = 0; r < 4; ++r)
                    Ped[(crow0 + r) * 68 + th + j * 16 + ccol] = acc[i][j][r];
        }
        __syncthreads();
        const int dchunk = d0 + c * 16;
        // 16 rows x 64 cols; each wave RMWs one full row (64 contiguous floats)
#pragma unroll
        for (int p = 0; p < 4; ++p) {
            const int row = p * 4 + (tid >> 6);
            const int col = tid & 63;
            const int gd = dchunk + row;
            if (gd < DP) {
                const int gt = t0 + col;
                if (fullT || gt < NP) {
                    const size_t idx = (size_t)gd * NP + gt;
                    Ob[idx] = Hs[idx] + inv_n * Ped[row * 68 + col];
                }
            }
        }
        __syncthreads();
    }
}

extern "C" void kernel_launch(void* const* d_in, const int* in_sizes, int n_in,
                              void* d_out, int out_size, void* d_ws, size_t ws_size,
                              hipStream_t stream) {
    const float* H = (const float*)d_in[0];
    const float* P = (const float*)d_in[1];
    const float* Q = (const float*)d_in[2];
    float* out = (float*)d_out;

    __hip_bfloat16* Hb  = (__hip_bfloat16*)d_ws;                   // 16*320*2048
    __hip_bfloat16* Hbt = Hb  + (size_t)NB * HROWS * 2048;         // 16*2176*320
    __hip_bfloat16* G   = Hbt + (size_t)NB * TROWS * TPITCH;       // 16*288*288
    __hip_bfloat16* Pb  = G   + (size_t)NB * KLD * KLD;            // 288*288
    __hip_bfloat16* Qt  = Pb  + (size_t)KLD * KLD;                 // 288*288
    // W and Kb alias Hb's region (Hb is dead after gram_staged)
    __hip_bfloat16* W   = Hb;
    __hip_bfloat16* Kb  = Hb + (size_t)NB * KLD * KLD;

    conv_pq<<<dim3(5, 5, 2),   256, 0, stream>>>(P, Q, Pb, Qt);
    conv_h <<<dim3(34, 5, NB), 256, 0, stream>>>(H, Hb, Hbt);
    // G[b] = H-hat @ H-hat^T  (staged 64x64 tiles, in-block split-K x2)
    gram_staged<<<dim3(25, NB), 512, 0, stream>>>(Hb, G);
    // W[b] = P @ G[b]   (B-frags = G rows, valid by symmetry of G)
    mm_sk4<<<dim3(81, NB), 256, 0, stream>>>(Pb, G, W, 0, KLD * KLD);
    // Kb[b] = W[b] @ Q  (B-frags = Qt rows)
    mm_sk4<<<dim3(81, NB), 256, 0, stream>>>(W, Qt, Kb, KLD * KLD, 0);
    // out = H + (Kb @ H) / n   (64x64 tiles, XCD-swizzled 1-D grid)
    attn_v4<<<dim3(33 * 5 * NB), 256, 0, stream>>>(Kb, Hbt, H, out);
}

// Round 3
// 198.751 us; speedup vs baseline: 1.1011x; 1.1011x over previous
//
#include <hip/hip_runtime.h>
#include <hip/hip_bf16.h>

#define DP     257
#define NP     2049
#define NSEQ   2048
#define NB     16
#define KLD    288         // pitch for small matrices (shorts)
#define HROWS  320         // padded rows for Hb
#define TPITCH 320         // Hbt pitch in shorts: 640 B = 5 full 128B lines
#define TROWS  2176        // padded t rows for Hbt (17*128)
#define KPAD   40          // LDS row pitch (shorts)

typedef __attribute__((ext_vector_type(8))) short bf16x8;
typedef __attribute__((ext_vector_type(4))) short bf16x4;
typedef __attribute__((ext_vector_type(4))) float f32x4;

// ---------------------------------------------------------------------------
// Convert H -> Hb (row-major bf16, 320 x 2048, = masked H-hat)
//           -> Hbt (transposed bf16, 2176 x 320-pitch, zero-padded)
// ---------------------------------------------------------------------------
__global__ __launch_bounds__(256) void conv_h(const float* __restrict__ H,
                                              __hip_bfloat16* __restrict__ Hb,
                                              __hip_bfloat16* __restrict__ Hbt) {
    const int b  = blockIdx.z;
    const int t0 = blockIdx.x * 64;
    const int e0 = blockIdx.y * 64;
    const float* __restrict__ Hs = H + (size_t)b * DP * NP;
    __hip_bfloat16* __restrict__ Hbb  = Hb  + (size_t)b * HROWS * 2048;
    __hip_bfloat16* __restrict__ Hbtb = Hbt + (size_t)b * TROWS * TPITCH;

    __shared__ float tile[64][65];

    const int tl = threadIdx.x & 63;
    const int er = threadIdx.x >> 6;
#pragma unroll
    for (int r = 0; r < 16; ++r) {
        const int el = er + r * 4;        // 0..63
        const int ge = e0 + el;
        const int gt = t0 + tl;
        float v = 0.f;
        if (ge < DP && gt < NP) v = Hs[(size_t)ge * NP + gt];
        tile[el][tl] = v;
        if (ge < HROWS && gt < 2048) Hbb[(size_t)ge * 2048 + gt] = __float2bfloat16(v);
    }
    __syncthreads();
#pragma unroll
    for (int r = 0; r < 16; ++r) {
        const int ttl = er + r * 4;       // t-local
        const int gt = t0 + ttl;
        const int ge = e0 + tl;           // e-local = lane -> contiguous writes
        if (gt < TROWS && ge < TPITCH) {
            const float v = (ge < KLD) ? tile[tl][ttl] : 0.f;
            Hbtb[(size_t)gt * TPITCH + ge] = __float2bfloat16(v);
        }
    }
}

// ---------------------------------------------------------------------------
// Pb[m][k] = P[m][k] (bf16, zero-padded to 288x288); Qt[n][k] = Q[k][n]
// ---------------------------------------------------------------------------
__global__ __launch_bounds__(256) void conv_pq(const float* __restrict__ P,
                                               const float* __restrict__ Q,
                                               __hip_bfloat16* __restrict__ Pb,
                                               __hip_bfloat16* __restrict__ Qt) {
    const int c0 = blockIdx.x * 64;
    const int r0 = blockIdx.y * 64;
    const int tl = threadIdx.x & 63;
    const int rr = threadIdx.x >> 6;
    __shared__ float tile[64][65];

    if (blockIdx.z == 0) {
#pragma unroll
        for (int r = 0; r < 16; ++r) {
            const int m = r0 + rr + r * 4;
            const int k = c0 + tl;
            float v = (m < DP && k < DP) ? P[m * DP + k] : 0.f;
            if (m < KLD && k < KLD) Pb[m * KLD + k] = __float2bfloat16(v);
        }
    } else {
#pragma unroll
        for (int r = 0; r < 16; ++r) {
            const int k = r0 + rr + r * 4;
            const int n = c0 + tl;
            float v = (k < DP && n < DP) ? Q[k * DP + n] : 0.f;
            tile[k - r0][n - c0] = v;
        }
        __syncthreads();
#pragma unroll
        for (int r = 0; r < 16; ++r) {
            const int k = r0 + tl;
            const int n = c0 + rr + r * 4;
            if (n < KLD && k < KLD) Qt[n * KLD + k] = __float2bfloat16(tile[tl][n - c0]);
        }
    }
}

// ---------------------------------------------------------------------------
// Split-K x2 Gram: G[z][b] = Hb[b][:, z*1024 : (z+1)*1024] @ (same)^T
// 800 blocks (3.1/CU, was 1.6) x 512 threads, 16 K-chunks each (was 32).
// In-block split-K x2 retained (two 512-wide halves). Partials G0,G1 are
// each symmetric; they are summed inside mm_sk4's f32 accumulator.
// ---------------------------------------------------------------------------
__global__ __launch_bounds__(512, 4) void gram_staged(const __hip_bfloat16* __restrict__ Hb,
                                                      __hip_bfloat16* __restrict__ G) {
    const int b  = blockIdx.y;
    const int ks = blockIdx.z;           // K-segment: 0 or 1 (1024 wide)
    const int tm = blockIdx.x / 5;
    const int tn = blockIdx.x % 5;
    const int m0 = tm * 64, n0 = tn * 64;
    const int tid = threadIdx.x;
    const int wave = tid >> 6, lane = tid & 63;
    const int lrow = lane & 15, kq = (lane >> 4) * 8;
    const int hw = wave >> 2;            // compute half
    const int q  = wave & 3;             // quadrant
    const int mh = (q & 1) * 32, nh = (q >> 1) * 32;
    const int hs = tid >> 8;             // staging half
    const int t2 = tid & 255;
    const int sr = t2 >> 2;              // 0..63
    const int sc = (t2 & 3) * 8;         // 0,8,16,24

    __shared__ __align__(16) char smem[2 * 2 * 2 * 64 * KPAD * 2];  // 40960 B
    short* As = (short*)smem;                    // [buf][h][64][KPAD]
    short* Bs = (short*)(smem + 2 * 2 * 64 * KPAD * 2);
    float* red = (float*)smem;                   // [8][32][32] (reused after loop)

    const short* __restrict__ base = (const short*)(Hb + (size_t)b * HROWS * 2048);
    const int kbase = ks * 1024;

    auto aoff = [&](int buf, int h, int r) { return ((buf * 2 + h) * 64 + r) * KPAD; };

    f32x4 acc[2][2] = {};

    {
        const int kb = kbase + hs * 512;
        *(bf16x8*)&As[aoff(0, hs, sr) + sc] = *(const bf16x8*)(base + (size_t)(m0 + sr) * 2048 + kb + sc);
        *(bf16x8*)&Bs[aoff(0, hs, sr) + sc] = *(const bf16x8*)(base + (size_t)(n0 + sr) * 2048 + kb + sc);
    }
    __syncthreads();

    for (int kt = 0; kt < 16; ++kt) {
        const int cur = kt & 1, nxt = cur ^ 1;
        if (kt + 1 < 16) {
            const int kb = kbase + hs * 512 + (kt + 1) * 32;
            *(bf16x8*)&As[aoff(nxt, hs, sr) + sc] = *(const bf16x8*)(base + (size_t)(m0 + sr) * 2048 + kb + sc);
            *(bf16x8*)&Bs[aoff(nxt, hs, sr) + sc] = *(const bf16x8*)(base + (size_t)(n0 + sr) * 2048 + kb + sc);
        }
        bf16x8 a0 = *(const bf16x8*)&As[aoff(cur, hw, mh + lrow) + kq];
        bf16x8 a1 = *(const bf16x8*)&As[aoff(cur, hw, mh + 16 + lrow) + kq];
        bf16x8 b0 = *(const bf16x8*)&Bs[aoff(cur, hw, nh + lrow) + kq];
        bf16x8 b1 = *(const bf16x8*)&Bs[aoff(cur, hw, nh + 16 + lrow) + kq];
        acc[0][0] = __builtin_amdgcn_mfma_f32_16x16x32_bf16(a0, b0, acc[0][0], 0, 0, 0);
        acc[0][1] = __builtin_amdgcn_mfma_f32_16x16x32_bf16(a0, b1, acc[0][1], 0, 0, 0);
        acc[1][0] = __builtin_amdgcn_mfma_f32_16x16x32_bf16(a1, b0, acc[1][0], 0, 0, 0);
        acc[1][1] = __builtin_amdgcn_mfma_f32_16x16x32_bf16(a1, b1, acc[1][1], 0, 0, 0);
        __syncthreads();
    }

    const int ccol  = lane & 15;
    const int crow0 = (lane >> 4) * 4;
#pragma unroll
    for (int i = 0; i < 2; ++i)
#pragma unroll
        for (int j = 0; j < 2; ++j)
#pragma unroll
            for (int r = 0; r < 4; ++r)
                red[((wave * 32) + i * 16 + crow0 + r) * 32 + j * 16 + ccol] = acc[i][j][r];
    __syncthreads();

    const int q2  = tid >> 7;
    const int t7  = tid & 127;
    const int row = t7 >> 2;
    const int c8  = (t7 & 3) * 8;
    const int gm = m0 + (q2 & 1) * 32 + row;
    const int gn = n0 + (q2 >> 1) * 32 + c8;
    if (gm < KLD && gn < KLD) {
        __hip_bfloat16 o[8];
#pragma unroll
        for (int t = 0; t < 8; ++t) {
            const float v = red[((q2 * 32) + row) * 32 + c8 + t] +
                            red[(((q2 + 4) * 32) + row) * 32 + c8 + t];
            o[t] = __float2bfloat16((gm < DP && (gn + t) < DP) ? v : 0.f);
        }
        __hip_bfloat16* __restrict__ Gb = G + ((size_t)ks * NB + b) * KLD * KLD;
        *(bf16x8*)&Gb[gm * KLD + gn] = *(const bf16x8*)o;
    }
}

// ---------------------------------------------------------------------------
// C[b][m][n] = sum_k A[m][k] * B[n][k]  (ld=288), split-K x4 over nk chunks.
// Chunks 0..8 read B, chunks 9..17 read B2 (summing split-K Gram partials
// inside the f32 accumulator).
// ---------------------------------------------------------------------------
__global__ __launch_bounds__(256) void mm_sk4(const __hip_bfloat16* __restrict__ A,
                                              const __hip_bfloat16* __restrict__ B,
                                              const __hip_bfloat16* __restrict__ B2,
                                              __hip_bfloat16* __restrict__ C,
                                              int strideA, int strideB, int nk) {
    const int b  = blockIdx.y;
    const int tm = blockIdx.x / 9;
    const int tn = blockIdx.x % 9;
    const int s    = threadIdx.x >> 6;
    const int lane = threadIdx.x & 63;
    const int lrow = lane & 15;
    const int koff = (lane >> 4) * 8;
    const short* __restrict__ Ab  = (const short*)(A  + (size_t)b * strideA);
    const short* __restrict__ Bb  = (const short*)(B  + (size_t)b * strideB);
    const short* __restrict__ Bb2 = (const short*)(B2 + (size_t)b * strideB);
    const int m0 = tm * 32, n0 = tn * 32;

    __shared__ float red[4][32][32];

    f32x4 acc[2][2] = {};
    for (int kt = s; kt < nk; kt += 4) {
        const short* __restrict__ Bp = (kt < 9) ? Bb : Bb2;
        const int k0 = (kt % 9) * 32;
        const int ka = (kt % 9) * 32;
        bf16x8 a0 = *(const bf16x8*)(Ab + (m0 + lrow)      * KLD + ka + koff);
        bf16x8 a1 = *(const bf16x8*)(Ab + (m0 + 16 + lrow) * KLD + ka + koff);
        bf16x8 c0 = *(const bf16x8*)(Bp + (n0 + lrow)      * KLD + k0 + koff);
        bf16x8 c1 = *(const bf16x8*)(Bp + (n0 + 16 + lrow) * KLD + k0 + koff);
        acc[0][0] = __builtin_amdgcn_mfma_f32_16x16x32_bf16(a0, c0, acc[0][0], 0, 0, 0);
        acc[0][1] = __builtin_amdgcn_mfma_f32_16x16x32_bf16(a0, c1, acc[0][1], 0, 0, 0);
        acc[1][0] = __builtin_amdgcn_mfma_f32_16x16x32_bf16(a1, c0, acc[1][0], 0, 0, 0);
        acc[1][1] = __builtin_amdgcn_mfma_f32_16x16x32_bf16(a1, c1, acc[1][1], 0, 0, 0);
    }

    const int ccol  = lane & 15;
    const int crow0 = (lane >> 4) * 4;
#pragma unroll
    for (int i = 0; i < 2; ++i)
#pragma unroll
        for (int j = 0; j < 2; ++j)
#pragma unroll
            for (int r = 0; r < 4; ++r)
                red[s][i * 16 + crow0 + r][j * 16 + ccol] = acc[i][j][r];
    __syncthreads();

    const int row = threadIdx.x >> 3;
    const int c4  = (threadIdx.x & 7) * 4;
    float4 v0 = *(const float4*)&red[0][row][c4];
    float4 v1 = *(const float4*)&red[1][row][c4];
    float4 v2 = *(const float4*)&red[2][row][c4];
    float4 v3 = *(const float4*)&red[3][row][c4];
    float sum[4] = {v0.x + v1.x + v2.x + v3.x,
                    v0.y + v1.y + v2.y + v3.y,
                    v0.z + v1.z + v2.z + v3.z,
                    v0.w + v1.w + v2.w + v3.w};
    const int gm = m0 + row;
    const int gn = n0 + c4;
    __hip_bfloat16 o[4];
#pragma unroll
    for (int t = 0; t < 4; ++t) {
        const float v = (gm < DP && (gn + t) < DP) ? sum[t] : 0.f;
        o[t] = __float2bfloat16(v);
    }
    __hip_bfloat16* __restrict__ Cb = C + (size_t)b * KLD * KLD;
    *(bf16x4*)&Cb[gm * KLD + gn] = *(const bf16x4*)o;
}

// ---------------------------------------------------------------------------
// out[b][d][t] = H[b][d][t] + (1/n) * sum_e Kb[d][e] * Hbt[t][e]
// (v2 restored verbatim — proven 51.5 us configuration)
// ---------------------------------------------------------------------------
__global__ __launch_bounds__(256, 4) void attn_v2(const __hip_bfloat16* __restrict__ Kb,
                                                  const __hip_bfloat16* __restrict__ Hbt,
                                                  const float* __restrict__ H,
                                                  float* __restrict__ Out) {
    const int b  = blockIdx.z;
    const int d0 = blockIdx.y * 64;
    const int t0 = blockIdx.x * 128;
    const int tid = threadIdx.x;
    const int wave = tid >> 6, lane = tid & 63;
    const int lrow = lane & 15, kq = (lane >> 4) * 8;
    const int dh = (wave & 1) * 32;      // wave's d-half
    const int th = (wave >> 1) * 64;     // wave's t-half
    const int sr = tid >> 2;             // 0..63
    const int sc = (tid & 3) * 8;        // 0,8,16,24

    __shared__ __align__(16) char smem[(64 + 128) * KPAD * 2];  // 15360 B
    short* As = (short*)smem;                         // [64][KPAD]
    short* Bs = (short*)(smem + 64 * KPAD * 2);       // [128][KPAD]
    float* Ped = (float*)smem;                        // [16][132] epilogue (8448 B)

    const short* __restrict__ Ka = (const short*)(Kb  + (size_t)b * KLD * KLD);
    const short* __restrict__ Ta = (const short*)(Hbt + (size_t)b * TROWS * TPITCH);

    int rA = d0 + sr; if (rA > KLD - 1) rA = KLD - 1;   // Kb rows 257..287 are zeros

    f32x4 acc[2][4] = {};

    // stage chunk 0
    bf16x8 pA  = *(const bf16x8*)(Ka + (size_t)rA * KLD + sc);
    bf16x8 pB0 = *(const bf16x8*)(Ta + (size_t)(t0 + sr) * TPITCH + sc);
    bf16x8 pB1 = *(const bf16x8*)(Ta + (size_t)(t0 + 64 + sr) * TPITCH + sc);
    *(bf16x8*)&As[sr * KPAD + sc]        = pA;
    *(bf16x8*)&Bs[sr * KPAD + sc]        = pB0;
    *(bf16x8*)&Bs[(64 + sr) * KPAD + sc] = pB1;
    __syncthreads();

    for (int kt = 0; kt < 9; ++kt) {
        if (kt < 8) {   // register prefetch of next chunk (overlaps compute)
            const int e0 = (kt + 1) * 32;
            pA  = *(const bf16x8*)(Ka + (size_t)rA * KLD + e0 + sc);
            pB0 = *(const bf16x8*)(Ta + (size_t)(t0 + sr) * TPITCH + e0 + sc);
            pB1 = *(const bf16x8*)(Ta + (size_t)(t0 + 64 + sr) * TPITCH + e0 + sc);
        }
        bf16x8 af0 = *(const bf16x8*)&As[(dh + lrow) * KPAD + kq];
        bf16x8 af1 = *(const bf16x8*)&As[(dh + 16 + lrow) * KPAD + kq];
        bf16x8 bfr[4];
#pragma unroll
        for (int j = 0; j < 4; ++j)
            bfr[j] = *(const bf16x8*)&Bs[(th + j * 16 + lrow) * KPAD + kq];
#pragma unroll
        for (int j = 0; j < 4; ++j) {
            acc[0][j] = __builtin_amdgcn_mfma_f32_16x16x32_bf16(af0, bfr[j], acc[0][j], 0, 0, 0);
            acc[1][j] = __builtin_amdgcn_mfma_f32_16x16x32_bf16(af1, bfr[j], acc[1][j], 0, 0, 0);
        }
        __syncthreads();
        if (kt < 8) {
            *(bf16x8*)&As[sr * KPAD + sc]        = pA;
            *(bf16x8*)&Bs[sr * KPAD + sc]        = pB0;
            *(bf16x8*)&Bs[(64 + sr) * KPAD + sc] = pB1;
            __syncthreads();
        }
    }

    // epilogue: 4 chunks of 16 d-rows through LDS, coalesced RMW
    const float* __restrict__ Hs = H + (size_t)b * DP * NP;
    float* __restrict__ Ob = Out + (size_t)b * DP * NP;
    const float inv_n = 1.0f / (float)NSEQ;
    const int ccol  = lane & 15;
    const int crow0 = (lane >> 4) * 4;

#pragma unroll
    for (int c = 0; c < 4; ++c) {
        // waves whose d-half matches this chunk dump their i = (c&1) frags
        if ((wave & 1) == (c >> 1)) {
            const int i = c & 1;
#pragma unroll
            for (int j = 0; j < 4; ++j)
#pragma unroll
                for (int r = 0; r < 4; ++r)
                    Ped[(crow0 + r) * 132 + th + j * 16 + ccol] = acc[i][j][r];
        }
        __syncthreads();
        // RMW 16 rows x 128 cols: 2 passes of 8 rows; 32 lanes x 16B contiguous
#pragma unroll
        for (int p = 0; p < 2; ++p) {
            const int row = (tid >> 5) + p * 8;
            const int col = (tid & 31) * 4;
            const int gd = d0 + c * 16 + row;
            if (gd < DP) {
                const float* src = &Ped[row * 132 + col];
                const size_t base = (size_t)gd * NP;
#pragma unroll
                for (int cc = 0; cc < 4; ++cc) {
                    const int gt = t0 + col + cc;
                    if (gt < NP) {
                        const size_t idx = base + gt;
                        Ob[idx] = Hs[idx] + inv_n * src[cc];
                    }
                }
            }
        }
        __syncthreads();
    }
}

extern "C" void kernel_launch(void* const* d_in, const int* in_sizes, int n_in,
                              void* d_out, int out_size, void* d_ws, size_t ws_size,
                              hipStream_t stream) {
    const float* H = (const float*)d_in[0];
    const float* P = (const float*)d_in[1];
    const float* Q = (const float*)d_in[2];
    float* out = (float*)d_out;

    __hip_bfloat16* Hb  = (__hip_bfloat16*)d_ws;                   // 16*320*2048
    __hip_bfloat16* Hbt = Hb  + (size_t)NB * HROWS * 2048;         // 16*2176*320
    __hip_bfloat16* G0  = Hbt + (size_t)NB * TROWS * TPITCH;       // 16*288*288
    __hip_bfloat16* G1  = G0  + (size_t)NB * KLD * KLD;            // 16*288*288
    __hip_bfloat16* Pb  = G1  + (size_t)NB * KLD * KLD;            // 288*288
    __hip_bfloat16* Qt  = Pb  + (size_t)KLD * KLD;                 // 288*288
    // W and Kb alias Hb's region (Hb is dead after gram_staged)
    __hip_bfloat16* W   = Hb;
    __hip_bfloat16* Kb  = Hb + (size_t)NB * KLD * KLD;

    conv_pq<<<dim3(5, 5, 2),   256, 0, stream>>>(P, Q, Pb, Qt);
    conv_h <<<dim3(34, 5, NB), 256, 0, stream>>>(H, Hb, Hbt);
    // G0/G1[b] = split-K Gram partials (800 blocks, 3.1/CU)
    gram_staged<<<dim3(25, NB, 2), 512, 0, stream>>>(Hb, G0);
    // W[b] = P @ (G0[b]+G1[b])  (18 K-chunks; partial sum in f32 acc)
    mm_sk4<<<dim3(81, NB), 256, 0, stream>>>(Pb, G0, G1, W, 0, KLD * KLD, 18);
    // Kb[b] = W[b] @ Q  (B-frags = Qt rows)
    mm_sk4<<<dim3(81, NB), 256, 0, stream>>>(W, Qt, Qt, Kb, KLD * KLD, 0, 9);
    // out = H + (Kb @ H) / n
    attn_v2<<<dim3(17, 5, NB), 256, 0, stream>>>(Kb, Hbt, H, out);
}

// Round 4
// 188.820 us; speedup vs baseline: 1.1590x; 1.0526x over previous
//
#include <hip/hip_runtime.h>
#include <hip/hip_bf16.h>

#define DP     257
#define NP     2049
#define NSEQ   2048
#define NB     16
#define KLD    288         // pitch for small matrices (shorts)
#define HROWS  320         // padded rows for Hb
#define TPITCH 320         // Hbt pitch in shorts: 640 B = 5 full 128B lines
#define TROWS  2176        // padded t rows for Hbt (17*128)
#define KPAD   40          // LDS row pitch (shorts)

typedef __attribute__((ext_vector_type(8))) short bf16x8;
typedef __attribute__((ext_vector_type(4))) short bf16x4;
typedef __attribute__((ext_vector_type(4))) float f32x4;

// ---------------------------------------------------------------------------
// Fused conversion kernel.
//  z < NB : H -> Hb (row-major bf16, masked H-hat) and Hbt (transposed)
//  z == NB: bx<5 -> Pb[m][k]=P (zero-padded 288x288); bx in 5..9 -> Qt[n][k]=Q[k][n]
// ---------------------------------------------------------------------------
__global__ __launch_bounds__(256) void conv_all(const float* __restrict__ H,
                                                const float* __restrict__ P,
                                                const float* __restrict__ Q,
                                                __hip_bfloat16* __restrict__ Hb,
                                                __hip_bfloat16* __restrict__ Hbt,
                                                __hip_bfloat16* __restrict__ Pb,
                                                __hip_bfloat16* __restrict__ Qt) {
    const int z  = blockIdx.z;
    const int tl = threadIdx.x & 63;
    const int er = threadIdx.x >> 6;
    __shared__ float tile[64][65];

    if (z < NB) {
        const int b  = z;
        const int t0 = blockIdx.x * 64;
        const int e0 = blockIdx.y * 64;
        const float* __restrict__ Hs = H + (size_t)b * DP * NP;
        __hip_bfloat16* __restrict__ Hbb  = Hb  + (size_t)b * HROWS * 2048;
        __hip_bfloat16* __restrict__ Hbtb = Hbt + (size_t)b * TROWS * TPITCH;

#pragma unroll
        for (int r = 0; r < 16; ++r) {
            const int el = er + r * 4;        // 0..63
            const int ge = e0 + el;
            const int gt = t0 + tl;
            float v = 0.f;
            if (ge < DP && gt < NP) v = Hs[(size_t)ge * NP + gt];
            tile[el][tl] = v;
            if (ge < HROWS && gt < 2048) Hbb[(size_t)ge * 2048 + gt] = __float2bfloat16(v);
        }
        __syncthreads();
#pragma unroll
        for (int r = 0; r < 16; ++r) {
            const int ttl = er + r * 4;       // t-local
            const int gt = t0 + ttl;
            const int ge = e0 + tl;           // e-local = lane -> contiguous writes
            if (gt < TROWS && ge < TPITCH) {
                const float v = (ge < KLD) ? tile[tl][ttl] : 0.f;
                Hbtb[(size_t)gt * TPITCH + ge] = __float2bfloat16(v);
            }
        }
        return;
    }

    // z == NB: P/Q conversion (50 blocks ride along)
    const int bx = blockIdx.x;
    if (bx >= 10) return;
    const int r0 = blockIdx.y * 64;
    if (bx < 5) {
        const int c0 = bx * 64;
#pragma unroll
        for (int r = 0; r < 16; ++r) {
            const int m = r0 + er + r * 4;
            const int k = c0 + tl;
            float v = (m < DP && k < DP) ? P[m * DP + k] : 0.f;
            if (m < KLD && k < KLD) Pb[m * KLD + k] = __float2bfloat16(v);
        }
    } else {
        const int c0 = (bx - 5) * 64;
#pragma unroll
        for (int r = 0; r < 16; ++r) {
            const int k = r0 + er + r * 4;
            const int n = c0 + tl;
            float v = (k < DP && n < DP) ? Q[k * DP + n] : 0.f;
            tile[k - r0][n - c0] = v;
        }
        __syncthreads();
#pragma unroll
        for (int r = 0; r < 16; ++r) {
            const int k = r0 + tl;
            const int n = c0 + er + r * 4;
            if (n < KLD && k < KLD) Qt[n * KLD + k] = __float2bfloat16(tile[tl][n - c0]);
        }
    }
}

// ---------------------------------------------------------------------------
// G[b] = Hb[b] @ Hb[b]^T, staged 64x64 tiles, 512 threads, split-K x2.
// (R0 configuration restored)
// ---------------------------------------------------------------------------
__global__ __launch_bounds__(512, 4) void gram_staged(const __hip_bfloat16* __restrict__ Hb,
                                                      __hip_bfloat16* __restrict__ G) {
    const int b  = blockIdx.y;
    const int tm = blockIdx.x / 5;
    const int tn = blockIdx.x % 5;
    const int m0 = tm * 64, n0 = tn * 64;
    const int tid = threadIdx.x;
    const int wave = tid >> 6, lane = tid & 63;
    const int lrow = lane & 15, kq = (lane >> 4) * 8;
    const int hw = wave >> 2;            // compute half
    const int q  = wave & 3;             // quadrant
    const int mh = (q & 1) * 32, nh = (q >> 1) * 32;
    const int hs = tid >> 8;             // staging half
    const int t2 = tid & 255;
    const int sr = t2 >> 2;              // 0..63
    const int sc = (t2 & 3) * 8;         // 0,8,16,24

    __shared__ __align__(16) char smem[2 * 2 * 2 * 64 * KPAD * 2];  // 40960 B
    short* As = (short*)smem;                    // [buf][h][64][KPAD]
    short* Bs = (short*)(smem + 2 * 2 * 64 * KPAD * 2);
    float* red = (float*)smem;                   // [8][32][32] (reused after loop)

    const short* __restrict__ base = (const short*)(Hb + (size_t)b * HROWS * 2048);

    auto aoff = [&](int buf, int h, int r) { return ((buf * 2 + h) * 64 + r) * KPAD; };

    f32x4 acc[2][2] = {};

    {
        const int kb = hs * 1024;
        *(bf16x8*)&As[aoff(0, hs, sr) + sc] = *(const bf16x8*)(base + (size_t)(m0 + sr) * 2048 + kb + sc);
        *(bf16x8*)&Bs[aoff(0, hs, sr) + sc] = *(const bf16x8*)(base + (size_t)(n0 + sr) * 2048 + kb + sc);
    }
    __syncthreads();

    for (int kt = 0; kt < 32; ++kt) {
        const int cur = kt & 1, nxt = cur ^ 1;
        if (kt + 1 < 32) {
            const int kb = hs * 1024 + (kt + 1) * 32;
            *(bf16x8*)&As[aoff(nxt, hs, sr) + sc] = *(const bf16x8*)(base + (size_t)(m0 + sr) * 2048 + kb + sc);
            *(bf16x8*)&Bs[aoff(nxt, hs, sr) + sc] = *(const bf16x8*)(base + (size_t)(n0 + sr) * 2048 + kb + sc);
        }
        bf16x8 a0 = *(const bf16x8*)&As[aoff(cur, hw, mh + lrow) + kq];
        bf16x8 a1 = *(const bf16x8*)&As[aoff(cur, hw, mh + 16 + lrow) + kq];
        bf16x8 b0 = *(const bf16x8*)&Bs[aoff(cur, hw, nh + lrow) + kq];
        bf16x8 b1 = *(const bf16x8*)&Bs[aoff(cur, hw, nh + 16 + lrow) + kq];
        acc[0][0] = __builtin_amdgcn_mfma_f32_16x16x32_bf16(a0, b0, acc[0][0], 0, 0, 0);
        acc[0][1] = __builtin_amdgcn_mfma_f32_16x16x32_bf16(a0, b1, acc[0][1], 0, 0, 0);
        acc[1][0] = __builtin_amdgcn_mfma_f32_16x16x32_bf16(a1, b0, acc[1][0], 0, 0, 0);
        acc[1][1] = __builtin_amdgcn_mfma_f32_16x16x32_bf16(a1, b1, acc[1][1], 0, 0, 0);
        __syncthreads();
    }

    const int ccol  = lane & 15;
    const int crow0 = (lane >> 4) * 4;
#pragma unroll
    for (int i = 0; i < 2; ++i)
#pragma unroll
        for (int j = 0; j < 2; ++j)
#pragma unroll
            for (int r = 0; r < 4; ++r)
                red[((wave * 32) + i * 16 + crow0 + r) * 32 + j * 16 + ccol] = acc[i][j][r];
    __syncthreads();

    const int q2  = tid >> 7;
    const int t7  = tid & 127;
    const int row = t7 >> 2;
    const int c8  = (t7 & 3) * 8;
    const int gm = m0 + (q2 & 1) * 32 + row;
    const int gn = n0 + (q2 >> 1) * 32 + c8;
    if (gm < KLD && gn < KLD) {
        __hip_bfloat16 o[8];
#pragma unroll
        for (int t = 0; t < 8; ++t) {
            const float v = red[((q2 * 32) + row) * 32 + c8 + t] +
                            red[(((q2 + 4) * 32) + row) * 32 + c8 + t];
            o[t] = __float2bfloat16((gm < DP && (gn + t) < DP) ? v : 0.f);
        }
        __hip_bfloat16* __restrict__ Gb = G + (size_t)b * KLD * KLD;
        *(bf16x8*)&Gb[gm * KLD + gn] = *(const bf16x8*)o;
    }
}

// ---------------------------------------------------------------------------
// C[b][m][n] = sum_k A[m][k] * B[n][k]  (K=288, ld=288), split-K x4.
// (R0 configuration restored)
// ---------------------------------------------------------------------------
__global__ __launch_bounds__(256) void mm_sk4(const __hip_bfloat16* __restrict__ A,
                                              const __hip_bfloat16* __restrict__ B,
                                              __hip_bfloat16* __restrict__ C,
                                              int strideA, int strideB) {
    const int b  = blockIdx.y;
    const int tm = blockIdx.x / 9;
    const int tn = blockIdx.x % 9;
    const int s    = threadIdx.x >> 6;
    const int lane = threadIdx.x & 63;
    const int lrow = lane & 15;
    const int koff = (lane >> 4) * 8;
    const short* __restrict__ Ab = (const short*)(A + (size_t)b * strideA);
    const short* __restrict__ Bb = (const short*)(B + (size_t)b * strideB);
    const int m0 = tm * 32, n0 = tn * 32;

    __shared__ float red[4][32][32];

    f32x4 acc[2][2] = {};
    for (int kt = s; kt < 9; kt += 4) {
        const int k0 = kt * 32;
        bf16x8 a0 = *(const bf16x8*)(Ab + (m0 + lrow)      * KLD + k0 + koff);
        bf16x8 a1 = *(const bf16x8*)(Ab + (m0 + 16 + lrow) * KLD + k0 + koff);
        bf16x8 c0 = *(const bf16x8*)(Bb + (n0 + lrow)      * KLD + k0 + koff);
        bf16x8 c1 = *(const bf16x8*)(Bb + (n0 + 16 + lrow) * KLD + k0 + koff);
        acc[0][0] = __builtin_amdgcn_mfma_f32_16x16x32_bf16(a0, c0, acc[0][0], 0, 0, 0);
        acc[0][1] = __builtin_amdgcn_mfma_f32_16x16x32_bf16(a0, c1, acc[0][1], 0, 0, 0);
        acc[1][0] = __builtin_amdgcn_mfma_f32_16x16x32_bf16(a1, c0, acc[1][0], 0, 0, 0);
        acc[1][1] = __builtin_amdgcn_mfma_f32_16x16x32_bf16(a1, c1, acc[1][1], 0, 0, 0);
    }

    const int ccol  = lane & 15;
    const int crow0 = (lane >> 4) * 4;
#pragma unroll
    for (int i = 0; i < 2; ++i)
#pragma unroll
        for (int j = 0; j < 2; ++j)
#pragma unroll
            for (int r = 0; r < 4; ++r)
                red[s][i * 16 + crow0 + r][j * 16 + ccol] = acc[i][j][r];
    __syncthreads();

    const int row = threadIdx.x >> 3;
    const int c4  = (threadIdx.x & 7) * 4;
    float4 v0 = *(const float4*)&red[0][row][c4];
    float4 v1 = *(const float4*)&red[1][row][c4];
    float4 v2 = *(const float4*)&red[2][row][c4];
    float4 v3 = *(const float4*)&red[3][row][c4];
    float sum[4] = {v0.x + v1.x + v2.x + v3.x,
                    v0.y + v1.y + v2.y + v3.y,
                    v0.z + v1.z + v2.z + v3.z,
                    v0.w + v1.w + v2.w + v3.w};
    const int gm = m0 + row;
    const int gn = n0 + c4;
    __hip_bfloat16 o[4];
#pragma unroll
    for (int t = 0; t < 4; ++t) {
        const float v = (gm < DP && (gn + t) < DP) ? sum[t] : 0.f;
        o[t] = __float2bfloat16(v);
    }
    __hip_bfloat16* __restrict__ Cb = C + (size_t)b * KLD * KLD;
    *(bf16x4*)&Cb[gm * KLD + gn] = *(const bf16x4*)o;
}

// ---------------------------------------------------------------------------
// out[b][d][t] = H[b][d][t] + (1/n) * sum_e Kb[d][e] * Hbt[t][e]
// (v2 verbatim, with a batch offset so it can be launched as two halves —
//  measurement aid: frees top-5 profiler slots for the other kernels)
// ---------------------------------------------------------------------------
__global__ __launch_bounds__(256, 4) void attn_v2(const __hip_bfloat16* __restrict__ Kb,
                                                  const __hip_bfloat16* __restrict__ Hbt,
                                                  const float* __restrict__ H,
                                                  float* __restrict__ Out,
                                                  int zoff) {
    const int b  = blockIdx.z + zoff;
    const int d0 = blockIdx.y * 64;
    const int t0 = blockIdx.x * 128;
    const int tid = threadIdx.x;
    const int wave = tid >> 6, lane = tid & 63;
    const int lrow = lane & 15, kq = (lane >> 4) * 8;
    const int dh = (wave & 1) * 32;      // wave's d-half
    const int th = (wave >> 1) * 64;     // wave's t-half
    const int sr = tid >> 2;             // 0..63
    const int sc = (tid & 3) * 8;        // 0,8,16,24

    __shared__ __align__(16) char smem[(64 + 128) * KPAD * 2];  // 15360 B
    short* As = (short*)smem;                         // [64][KPAD]
    short* Bs = (short*)(smem + 64 * KPAD * 2);       // [128][KPAD]
    float* Ped = (float*)smem;                        // [16][132] epilogue (8448 B)

    const short* __restrict__ Ka = (const short*)(Kb  + (size_t)b * KLD * KLD);
    const short* __restrict__ Ta = (const short*)(Hbt + (size_t)b * TROWS * TPITCH);

    int rA = d0 + sr; if (rA > KLD - 1) rA = KLD - 1;   // Kb rows 257..287 are zeros

    f32x4 acc[2][4] = {};

    // stage chunk 0
    bf16x8 pA  = *(const bf16x8*)(Ka + (size_t)rA * KLD + sc);
    bf16x8 pB0 = *(const bf16x8*)(Ta + (size_t)(t0 + sr) * TPITCH + sc);
    bf16x8 pB1 = *(const bf16x8*)(Ta + (size_t)(t0 + 64 + sr) * TPITCH + sc);
    *(bf16x8*)&As[sr * KPAD + sc]        = pA;
    *(bf16x8*)&Bs[sr * KPAD + sc]        = pB0;
    *(bf16x8*)&Bs[(64 + sr) * KPAD + sc] = pB1;
    __syncthreads();

    for (int kt = 0; kt < 9; ++kt) {
        if (kt < 8) {   // register prefetch of next chunk (overlaps compute)
            const int e0 = (kt + 1) * 32;
            pA  = *(const bf16x8*)(Ka + (size_t)rA * KLD + e0 + sc);
            pB0 = *(const bf16x8*)(Ta + (size_t)(t0 + sr) * TPITCH + e0 + sc);
            pB1 = *(const bf16x8*)(Ta + (size_t)(t0 + 64 + sr) * TPITCH + e0 + sc);
        }
        bf16x8 af0 = *(const bf16x8*)&As[(dh + lrow) * KPAD + kq];
        bf16x8 af1 = *(const bf16x8*)&As[(dh + 16 + lrow) * KPAD + kq];
        bf16x8 bfr[4];
#pragma unroll
        for (int j = 0; j < 4; ++j)
            bfr[j] = *(const bf16x8*)&Bs[(th + j * 16 + lrow) * KPAD + kq];
#pragma unroll
        for (int j = 0; j < 4; ++j) {
            acc[0][j] = __builtin_amdgcn_mfma_f32_16x16x32_bf16(af0, bfr[j], acc[0][j], 0, 0, 0);
            acc[1][j] = __builtin_amdgcn_mfma_f32_16x16x32_bf16(af1, bfr[j], acc[1][j], 0, 0, 0);
        }
        __syncthreads();
        if (kt < 8) {
            *(bf16x8*)&As[sr * KPAD + sc]        = pA;
            *(bf16x8*)&Bs[sr * KPAD + sc]        = pB0;
            *(bf16x8*)&Bs[(64 + sr) * KPAD + sc] = pB1;
            __syncthreads();
        }
    }

    // epilogue: 4 chunks of 16 d-rows through LDS, coalesced RMW
    const float* __restrict__ Hs = H + (size_t)b * DP * NP;
    float* __restrict__ Ob = Out + (size_t)b * DP * NP;
    const float inv_n = 1.0f / (float)NSEQ;
    const int ccol  = lane & 15;
    const int crow0 = (lane >> 4) * 4;

#pragma unroll
    for (int c = 0; c < 4; ++c) {
        // waves whose d-half matches this chunk dump their i = (c&1) frags
        if ((wave & 1) == (c >> 1)) {
            const int i = c & 1;
#pragma unroll
            for (int j = 0; j < 4; ++j)
#pragma unroll
                for (int r = 0; r < 4; ++r)
                    Ped[(crow0 + r) * 132 + th + j * 16 + ccol] = acc[i][j][r];
        }
        __syncthreads();
        // RMW 16 rows x 128 cols: 2 passes of 8 rows; 32 lanes x 16B contiguous
#pragma unroll
        for (int p = 0; p < 2; ++p) {
            const int row = (tid >> 5) + p * 8;
            const int col = (tid & 31) * 4;
            const int gd = d0 + c * 16 + row;
            if (gd < DP) {
                const float* src = &Ped[row * 132 + col];
                const size_t base = (size_t)gd * NP;
#pragma unroll
                for (int cc = 0; cc < 4; ++cc) {
                    const int gt = t0 + col + cc;
                    if (gt < NP) {
                        const size_t idx = base + gt;
                        Ob[idx] = Hs[idx] + inv_n * src[cc];
                    }
                }
            }
        }
        __syncthreads();
    }
}

extern "C" void kernel_launch(void* const* d_in, const int* in_sizes, int n_in,
                              void* d_out, int out_size, void* d_ws, size_t ws_size,
                              hipStream_t stream) {
    const float* H = (const float*)d_in[0];
    const float* P = (const float*)d_in[1];
    const float* Q = (const float*)d_in[2];
    float* out = (float*)d_out;

    __hip_bfloat16* Hb  = (__hip_bfloat16*)d_ws;                   // 16*320*2048
    __hip_bfloat16* Hbt = Hb  + (size_t)NB * HROWS * 2048;         // 16*2176*320
    __hip_bfloat16* G   = Hbt + (size_t)NB * TROWS * TPITCH;       // 16*288*288
    __hip_bfloat16* Pb  = G   + (size_t)NB * KLD * KLD;            // 288*288
    __hip_bfloat16* Qt  = Pb  + (size_t)KLD * KLD;                 // 288*288
    // W and Kb alias Hb's region (Hb is dead after gram_staged)
    __hip_bfloat16* W   = Hb;
    __hip_bfloat16* Kb  = Hb + (size_t)NB * KLD * KLD;

    // fused conversions: H (z<16) + P/Q (z==16) in one launch
    conv_all<<<dim3(34, 5, NB + 1), 256, 0, stream>>>(H, P, Q, Hb, Hbt, Pb, Qt);
    // G[b] = H-hat @ H-hat^T  (staged 64x64 tiles, in-block split-K x2)
    gram_staged<<<dim3(25, NB), 512, 0, stream>>>(Hb, G);
    // W[b] = P @ G[b]   (B-frags = G rows, valid by symmetry of G)
    mm_sk4<<<dim3(81, NB), 256, 0, stream>>>(Pb, G, W, 0, KLD * KLD);
    // Kb[b] = W[b] @ Q  (B-frags = Qt rows)
    mm_sk4<<<dim3(81, NB), 256, 0, stream>>>(W, Qt, Kb, KLD * KLD, 0);
    // out = H + (Kb @ H) / n  — split into two half-batch launches so the
    // profiler's top-5 slots can surface the other kernels (measurement aid)
    attn_v2<<<dim3(17, 5, 8), 256, 0, stream>>>(Kb, Hbt, H, out, 0);
    attn_v2<<<dim3(17, 5, 8), 256, 0, stream>>>(Kb, Hbt, H, out, 8);
}

// Round 5
// 173.668 us; speedup vs baseline: 1.2602x; 1.0873x over previous
//
#include <hip/hip_runtime.h>
#include <hip/hip_bf16.h>

#define DP     257
#define NP     2049
#define NSEQ   2048
#define NB     16
#define KLD    288         // pitch for small matrices (shorts)
#define HROWS  320         // padded rows for Hb
#define TPITCH 320         // Hbt pitch in shorts: 640 B = 5 full 128B lines
#define TROWS  2176        // padded t rows for Hbt (17*128)
#define KPAD   40          // LDS row pitch (shorts)

typedef __attribute__((ext_vector_type(8))) short bf16x8;
typedef __attribute__((ext_vector_type(4))) short bf16x4;
typedef __attribute__((ext_vector_type(4))) float f32x4;

// ---------------------------------------------------------------------------
// Fused conversion kernel.
//  z < NB : H -> Hb (row-major bf16, masked H-hat) and Hbt (transposed)
//  z == NB: bx<5 -> Pb[m][k]=P (zero-padded 288x288); bx in 5..9 -> Qt[n][k]=Q[k][n]
// ---------------------------------------------------------------------------
__global__ __launch_bounds__(256) void conv_all(const float* __restrict__ H,
                                                const float* __restrict__ P,
                                                const float* __restrict__ Q,
                                                __hip_bfloat16* __restrict__ Hb,
                                                __hip_bfloat16* __restrict__ Hbt,
                                                __hip_bfloat16* __restrict__ Pb,
                                                __hip_bfloat16* __restrict__ Qt) {
    const int z  = blockIdx.z;
    const int tl = threadIdx.x & 63;
    const int er = threadIdx.x >> 6;
    __shared__ float tile[64][65];

    if (z < NB) {
        const int b  = z;
        const int t0 = blockIdx.x * 64;
        const int e0 = blockIdx.y * 64;
        const float* __restrict__ Hs = H + (size_t)b * DP * NP;
        __hip_bfloat16* __restrict__ Hbb  = Hb  + (size_t)b * HROWS * 2048;
        __hip_bfloat16* __restrict__ Hbtb = Hbt + (size_t)b * TROWS * TPITCH;

#pragma unroll
        for (int r = 0; r < 16; ++r) {
            const int el = er + r * 4;        // 0..63
            const int ge = e0 + el;
            const int gt = t0 + tl;
            float v = 0.f;
            if (ge < DP && gt < NP) v = Hs[(size_t)ge * NP + gt];
            tile[el][tl] = v;
            if (ge < HROWS && gt < 2048) Hbb[(size_t)ge * 2048 + gt] = __float2bfloat16(v);
        }
        __syncthreads();
#pragma unroll
        for (int r = 0; r < 16; ++r) {
            const int ttl = er + r * 4;       // t-local
            const int gt = t0 + ttl;
            const int ge = e0 + tl;           // e-local = lane -> contiguous writes
            if (gt < TROWS && ge < TPITCH) {
                const float v = (ge < KLD) ? tile[tl][ttl] : 0.f;
                Hbtb[(size_t)gt * TPITCH + ge] = __float2bfloat16(v);
            }
        }
        return;
    }

    // z == NB: P/Q conversion (50 blocks ride along)
    const int bx = blockIdx.x;
    if (bx >= 10) return;
    const int r0 = blockIdx.y * 64;
    if (bx < 5) {
        const int c0 = bx * 64;
#pragma unroll
        for (int r = 0; r < 16; ++r) {
            const int m = r0 + er + r * 4;
            const int k = c0 + tl;
            float v = (m < DP && k < DP) ? P[m * DP + k] : 0.f;
            if (m < KLD && k < KLD) Pb[m * KLD + k] = __float2bfloat16(v);
        }
    } else {
        const int c0 = (bx - 5) * 64;
#pragma unroll
        for (int r = 0; r < 16; ++r) {
            const int k = r0 + er + r * 4;
            const int n = c0 + tl;
            float v = (k < DP && n < DP) ? Q[k * DP + n] : 0.f;
            tile[k - r0][n - c0] = v;
        }
        __syncthreads();
#pragma unroll
        for (int r = 0; r < 16; ++r) {
            const int k = r0 + tl;
            const int n = c0 + er + r * 4;
            if (n < KLD && k < KLD) Qt[n * KLD + k] = __float2bfloat16(tile[tl][n - c0]);
        }
    }
}

// ---------------------------------------------------------------------------
// G[b] = Hb[b] @ Hb[b]^T, staged 64x64 tiles, 512 threads, split-K x2.
// ---------------------------------------------------------------------------
__global__ __launch_bounds__(512, 4) void gram_staged(const __hip_bfloat16* __restrict__ Hb,
                                                      __hip_bfloat16* __restrict__ G) {
    const int b  = blockIdx.y;
    const int tm = blockIdx.x / 5;
    const int tn = blockIdx.x % 5;
    const int m0 = tm * 64, n0 = tn * 64;
    const int tid = threadIdx.x;
    const int wave = tid >> 6, lane = tid & 63;
    const int lrow = lane & 15, kq = (lane >> 4) * 8;
    const int hw = wave >> 2;            // compute half
    const int q  = wave & 3;             // quadrant
    const int mh = (q & 1) * 32, nh = (q >> 1) * 32;
    const int hs = tid >> 8;             // staging half
    const int t2 = tid & 255;
    const int sr = t2 >> 2;              // 0..63
    const int sc = (t2 & 3) * 8;         // 0,8,16,24

    __shared__ __align__(16) char smem[2 * 2 * 2 * 64 * KPAD * 2];  // 40960 B
    short* As = (short*)smem;                    // [buf][h][64][KPAD]
    short* Bs = (short*)(smem + 2 * 2 * 64 * KPAD * 2);
    float* red = (float*)smem;                   // [8][32][32] (reused after loop)

    const short* __restrict__ base = (const short*)(Hb + (size_t)b * HROWS * 2048);

    auto aoff = [&](int buf, int h, int r) { return ((buf * 2 + h) * 64 + r) * KPAD; };

    f32x4 acc[2][2] = {};

    {
        const int kb = hs * 1024;
        *(bf16x8*)&As[aoff(0, hs, sr) + sc] = *(const bf16x8*)(base + (size_t)(m0 + sr) * 2048 + kb + sc);
        *(bf16x8*)&Bs[aoff(0, hs, sr) + sc] = *(const bf16x8*)(base + (size_t)(n0 + sr) * 2048 + kb + sc);
    }
    __syncthreads();

    for (int kt = 0; kt < 32; ++kt) {
        const int cur = kt & 1, nxt = cur ^ 1;
        if (kt + 1 < 32) {
            const int kb = hs * 1024 + (kt + 1) * 32;
            *(bf16x8*)&As[aoff(nxt, hs, sr) + sc] = *(const bf16x8*)(base + (size_t)(m0 + sr) * 2048 + kb + sc);
            *(bf16x8*)&Bs[aoff(nxt, hs, sr) + sc] = *(const bf16x8*)(base + (size_t)(n0 + sr) * 2048 + kb + sc);
        }
        bf16x8 a0 = *(const bf16x8*)&As[aoff(cur, hw, mh + lrow) + kq];
        bf16x8 a1 = *(const bf16x8*)&As[aoff(cur, hw, mh + 16 + lrow) + kq];
        bf16x8 b0 = *(const bf16x8*)&Bs[aoff(cur, hw, nh + lrow) + kq];
        bf16x8 b1 = *(const bf16x8*)&Bs[aoff(cur, hw, nh + 16 + lrow) + kq];
        acc[0][0] = __builtin_amdgcn_mfma_f32_16x16x32_bf16(a0, b0, acc[0][0], 0, 0, 0);
        acc[0][1] = __builtin_amdgcn_mfma_f32_16x16x32_bf16(a0, b1, acc[0][1], 0, 0, 0);
        acc[1][0] = __builtin_amdgcn_mfma_f32_16x16x32_bf16(a1, b0, acc[1][0], 0, 0, 0);
        acc[1][1] = __builtin_amdgcn_mfma_f32_16x16x32_bf16(a1, b1, acc[1][1], 0, 0, 0);
        __syncthreads();
    }

    const int ccol  = lane & 15;
    const int crow0 = (lane >> 4) * 4;
#pragma unroll
    for (int i = 0; i < 2; ++i)
#pragma unroll
        for (int j = 0; j < 2; ++j)
#pragma unroll
            for (int r = 0; r < 4; ++r)
                red[((wave * 32) + i * 16 + crow0 + r) * 32 + j * 16 + ccol] = acc[i][j][r];
    __syncthreads();

    const int q2  = tid >> 7;
    const int t7  = tid & 127;
    const int row = t7 >> 2;
    const int c8  = (t7 & 3) * 8;
    const int gm = m0 + (q2 & 1) * 32 + row;
    const int gn = n0 + (q2 >> 1) * 32 + c8;
    if (gm < KLD && gn < KLD) {
        __hip_bfloat16 o[8];
#pragma unroll
        for (int t = 0; t < 8; ++t) {
            const float v = red[((q2 * 32) + row) * 32 + c8 + t] +
                            red[(((q2 + 4) * 32) + row) * 32 + c8 + t];
            o[t] = __float2bfloat16((gm < DP && (gn + t) < DP) ? v : 0.f);
        }
        __hip_bfloat16* __restrict__ Gb = G + (size_t)b * KLD * KLD;
        *(bf16x8*)&Gb[gm * KLD + gn] = *(const bf16x8*)o;
    }
}

// ---------------------------------------------------------------------------
// C[b][m][n] = sum_k A[m][k] * B[n][k]  (K=288, ld=288), split-K x4.
// ---------------------------------------------------------------------------
__global__ __launch_bounds__(256) void mm_sk4(const __hip_bfloat16* __restrict__ A,
                                              const __hip_bfloat16* __restrict__ B,
                                              __hip_bfloat16* __restrict__ C,
                                              int strideA, int strideB) {
    const int b  = blockIdx.y;
    const int tm = blockIdx.x / 9;
    const int tn = blockIdx.x % 9;
    const int s    = threadIdx.x >> 6;
    const int lane = threadIdx.x & 63;
    const int lrow = lane & 15;
    const int koff = (lane >> 4) * 8;
    const short* __restrict__ Ab = (const short*)(A + (size_t)b * strideA);
    const short* __restrict__ Bb = (const short*)(B + (size_t)b * strideB);
    const int m0 = tm * 32, n0 = tn * 32;

    __shared__ float red[4][32][32];

    f32x4 acc[2][2] = {};
    for (int kt = s; kt < 9; kt += 4) {
        const int k0 = kt * 32;
        bf16x8 a0 = *(const bf16x8*)(Ab + (m0 + lrow)      * KLD + k0 + koff);
        bf16x8 a1 = *(const bf16x8*)(Ab + (m0 + 16 + lrow) * KLD + k0 + koff);
        bf16x8 c0 = *(const bf16x8*)(Bb + (n0 + lrow)      * KLD + k0 + koff);
        bf16x8 c1 = *(const bf16x8*)(Bb + (n0 + 16 + lrow) * KLD + k0 + koff);
        acc[0][0] = __builtin_amdgcn_mfma_f32_16x16x32_bf16(a0, c0, acc[0][0], 0, 0, 0);
        acc[0][1] = __builtin_amdgcn_mfma_f32_16x16x32_bf16(a0, c1, acc[0][1], 0, 0, 0);
        acc[1][0] = __builtin_amdgcn_mfma_f32_16x16x32_bf16(a1, c0, acc[1][0], 0, 0, 0);
        acc[1][1] = __builtin_amdgcn_mfma_f32_16x16x32_bf16(a1, c1, acc[1][1], 0, 0, 0);
    }

    const int ccol  = lane & 15;
    const int crow0 = (lane >> 4) * 4;
#pragma unroll
    for (int i = 0; i < 2; ++i)
#pragma unroll
        for (int j = 0; j < 2; ++j)
#pragma unroll
            for (int r = 0; r < 4; ++r)
                red[s][i * 16 + crow0 + r][j * 16 + ccol] = acc[i][j][r];
    __syncthreads();

    const int row = threadIdx.x >> 3;
    const int c4  = (threadIdx.x & 7) * 4;
    float4 v0 = *(const float4*)&red[0][row][c4];
    float4 v1 = *(const float4*)&red[1][row][c4];
    float4 v2 = *(const float4*)&red[2][row][c4];
    float4 v3 = *(const float4*)&red[3][row][c4];
    float sum[4] = {v0.x + v1.x + v2.x + v3.x,
                    v0.y + v1.y + v2.y + v3.y,
                    v0.z + v1.z + v2.z + v3.z,
                    v0.w + v1.w + v2.w + v3.w};
    const int gm = m0 + row;
    const int gn = n0 + c4;
    __hip_bfloat16 o[4];
#pragma unroll
    for (int t = 0; t < 4; ++t) {
        const float v = (gm < DP && (gn + t) < DP) ? sum[t] : 0.f;
        o[t] = __float2bfloat16(v);
    }
    __hip_bfloat16* __restrict__ Cb = C + (size_t)b * KLD * KLD;
    *(bf16x4*)&Cb[gm * KLD + gn] = *(const bf16x4*)o;
}

// ---------------------------------------------------------------------------
// out[b][d][t] = H[b][d][t] + (1/n) * sum_e Kb[d][e] * Hbt[t][e]
//
// v5 = v2 geometry (64d x 128t, 4 waves) with the per-chunk stall removed:
//  * double-buffered LDS -> ONE barrier per chunk (write buf[cur^1] while
//    reading buf[cur]; buf[cur^1]'s readers finished at the previous barrier)
//  * 2-deep register prefetch: loads issued at chunk kt are ds_written at
//    kt+1, so the vmcnt wait sits a full chunk of MFMA+barrier after issue
//  * bijective XCD swizzle (1360 = 8*170): each XCD owns exactly 2 batches;
//    the 5 d-blocks sharing an Hbt t-panel are consecutive on one XCD
// ---------------------------------------------------------------------------
__global__ __launch_bounds__(256, 4) void attn_v5(const __hip_bfloat16* __restrict__ Kb,
                                                  const __hip_bfloat16* __restrict__ Hbt,
                                                  const float* __restrict__ H,
                                                  float* __restrict__ Out) {
    // XCD swizzle: 1360 blocks, 170 per XCD = 2 batches (85 = 17t x 5d each)
    const int id      = blockIdx.x;
    const int logical = (id & 7) * 170 + (id >> 3);
    const int b   = logical / 85;
    const int rem = logical % 85;
    const int t0  = (rem / 5) * 128;
    const int d0  = (rem % 5) * 64;

    const int tid = threadIdx.x;
    const int wave = tid >> 6, lane = tid & 63;
    const int lrow = lane & 15, kq = (lane >> 4) * 8;
    const int dh = (wave & 1) * 32;      // wave's d-half
    const int th = (wave >> 1) * 64;     // wave's t-half
    const int sr = tid >> 2;             // 0..63
    const int sc = (tid & 3) * 8;        // 0,8,16,24

    __shared__ __align__(16) char smem[2 * (64 + 128) * KPAD * 2];  // 30720 B
    // buffer i: A rows [0,64), B rows [64,192) at base i*192*KPAD (shorts)
    short* bufs = (short*)smem;
    float* Ped  = (float*)smem;          // [16][132] epilogue staging (reuse)

    const short* __restrict__ Ka = (const short*)(Kb  + (size_t)b * KLD * KLD);
    const short* __restrict__ Ta = (const short*)(Hbt + (size_t)b * TROWS * TPITCH);

    int rA = d0 + sr; if (rA > KLD - 1) rA = KLD - 1;   // Kb rows 257..287 are zeros
    const short* __restrict__ gA  = Ka + (size_t)rA * KLD + sc;
    const short* __restrict__ gB0 = Ta + (size_t)(t0 + sr) * TPITCH + sc;
    const short* __restrict__ gB1 = Ta + (size_t)(t0 + 64 + sr) * TPITCH + sc;

    auto Aoff = [&](int bi, int r) { return (bi * 192 + r) * KPAD; };
    auto Boff = [&](int bi, int r) { return (bi * 192 + 64 + r) * KPAD; };

    f32x4 acc[2][4] = {};

    // prologue: chunk 0 -> buf0 (direct), chunk 1 -> regs R
    {
        bf16x8 a = *(const bf16x8*)gA;
        bf16x8 x = *(const bf16x8*)gB0;
        bf16x8 y = *(const bf16x8*)gB1;
        *(bf16x8*)&bufs[Aoff(0, sr) + sc]      = a;
        *(bf16x8*)&bufs[Boff(0, sr) + sc]      = x;
        *(bf16x8*)&bufs[Boff(0, 64 + sr) + sc] = y;
    }
    bf16x8 rA1 = *(const bf16x8*)(gA  + 32);
    bf16x8 rB0 = *(const bf16x8*)(gB0 + 32);
    bf16x8 rB1 = *(const bf16x8*)(gB1 + 32);
    __syncthreads();

#pragma unroll
    for (int kt = 0; kt < 9; ++kt) {
        const int cur = kt & 1;
        // issue loads for chunk kt+2 (consumed at iteration kt+1's ds_write)
        bf16x8 nA, nB0, nB1;
        if (kt < 7) {
            const int e = (kt + 2) * 32;
            nA  = *(const bf16x8*)(gA  + e);
            nB0 = *(const bf16x8*)(gB0 + e);
            nB1 = *(const bf16x8*)(gB1 + e);
        }
        // compute on buf[cur]
        bf16x8 af0 = *(const bf16x8*)&bufs[Aoff(cur, dh + lrow) + kq];
        bf16x8 af1 = *(const bf16x8*)&bufs[Aoff(cur, dh + 16 + lrow) + kq];
        bf16x8 bfr[4];
#pragma unroll
        for (int j = 0; j < 4; ++j)
            bfr[j] = *(const bf16x8*)&bufs[Boff(cur, th + j * 16 + lrow) + kq];
#pragma unroll
        for (int j = 0; j < 4; ++j) {
            acc[0][j] = __builtin_amdgcn_mfma_f32_16x16x32_bf16(af0, bfr[j], acc[0][j], 0, 0, 0);
            acc[1][j] = __builtin_amdgcn_mfma_f32_16x16x32_bf16(af1, bfr[j], acc[1][j], 0, 0, 0);
        }
        // write chunk kt+1 (loaded a full iteration ago) into the other buffer
        if (kt < 8) {
            *(bf16x8*)&bufs[Aoff(cur ^ 1, sr) + sc]      = rA1;
            *(bf16x8*)&bufs[Boff(cur ^ 1, sr) + sc]      = rB0;
            *(bf16x8*)&bufs[Boff(cur ^ 1, 64 + sr) + sc] = rB1;
        }
        __syncthreads();                  // ONE barrier per chunk
        if (kt < 7) { rA1 = nA; rB0 = nB0; rB1 = nB1; }
    }

    // epilogue: 4 chunks of 16 d-rows through LDS, coalesced RMW
    const float* __restrict__ Hs = H + (size_t)b * DP * NP;
    float* __restrict__ Ob = Out + (size_t)b * DP * NP;
    const float inv_n = 1.0f / (float)NSEQ;
    const int ccol  = lane & 15;
    const int crow0 = (lane >> 4) * 4;

#pragma unroll
    for (int c = 0; c < 4; ++c) {
        // waves whose d-half matches this chunk dump their i = (c&1) frags
        if ((wave & 1) == (c >> 1)) {
            const int i = c & 1;
#pragma unroll
            for (int j = 0; j < 4; ++j)
#pragma unroll
                for (int r = 0; r < 4; ++r)
                    Ped[(crow0 + r) * 132 + th + j * 16 + ccol] = acc[i][j][r];
        }
        __syncthreads();
        // RMW 16 rows x 128 cols: 2 passes of 8 rows; 32 lanes x 16B contiguous
#pragma unroll
        for (int p = 0; p < 2; ++p) {
            const int row = (tid >> 5) + p * 8;
            const int col = (tid & 31) * 4;
            const int gd = d0 + c * 16 + row;
            if (gd < DP) {
                const float* src = &Ped[row * 132 + col];
                const size_t base = (size_t)gd * NP;
#pragma unroll
                for (int cc = 0; cc < 4; ++cc) {
                    const int gt = t0 + col + cc;
                    if (gt < NP) {
                        const size_t idx = base + gt;
                        Ob[idx] = Hs[idx] + inv_n * src[cc];
                    }
                }
            }
        }
        __syncthreads();
    }
}

extern "C" void kernel_launch(void* const* d_in, const int* in_sizes, int n_in,
                              void* d_out, int out_size, void* d_ws, size_t ws_size,
                              hipStream_t stream) {
    const float* H = (const float*)d_in[0];
    const float* P = (const float*)d_in[1];
    const float* Q = (const float*)d_in[2];
    float* out = (float*)d_out;

    __hip_bfloat16* Hb  = (__hip_bfloat16*)d_ws;                   // 16*320*2048
    __hip_bfloat16* Hbt = Hb  + (size_t)NB * HROWS * 2048;         // 16*2176*320
    __hip_bfloat16* G   = Hbt + (size_t)NB * TROWS * TPITCH;       // 16*288*288
    __hip_bfloat16* Pb  = G   + (size_t)NB * KLD * KLD;            // 288*288
    __hip_bfloat16* Qt  = Pb  + (size_t)KLD * KLD;                 // 288*288
    // W and Kb alias Hb's region (Hb is dead after gram_staged)
    __hip_bfloat16* W   = Hb;
    __hip_bfloat16* Kb  = Hb + (size_t)NB * KLD * KLD;

    // fused conversions: H (z<16) + P/Q (z==16) in one launch
    conv_all<<<dim3(34, 5, NB + 1), 256, 0, stream>>>(H, P, Q, Hb, Hbt, Pb, Qt);
    // G[b] = H-hat @ H-hat^T  (staged 64x64 tiles, in-block split-K x2)
    gram_staged<<<dim3(25, NB), 512, 0, stream>>>(Hb, G);
    // W[b] = P @ G[b]   (B-frags = G rows, valid by symmetry of G)
    mm_sk4<<<dim3(81, NB), 256, 0, stream>>>(Pb, G, W, 0, KLD * KLD);
    // Kb[b] = W[b] @ Q  (B-frags = Qt rows)
    mm_sk4<<<dim3(81, NB), 256, 0, stream>>>(W, Qt, Kb, KLD * KLD, 0);
    // out = H + (Kb @ H) / n  (single launch, XCD-swizzled 1-D grid)
    attn_v5<<<dim3(17 * 5 * NB), 256, 0, stream>>>(Kb, Hbt, H, out);
}

// Round 6
// 173.586 us; speedup vs baseline: 1.2607x; 1.0005x over previous
//
#include <hip/hip_runtime.h>
#include <hip/hip_bf16.h>

#define DP     257
#define NP     2049
#define NSEQ   2048
#define NB     16
#define KLD    288         // pitch for small matrices (shorts)
#define HROWS  320         // padded rows for Hb
#define TPITCH 320         // Hbt pitch in shorts: 640 B = 5 full 128B lines
#define TROWS  2176        // padded t rows for Hbt (17*128)
#define KPAD   40          // LDS row pitch (shorts)

typedef __attribute__((ext_vector_type(8))) short bf16x8;
typedef __attribute__((ext_vector_type(4))) short bf16x4;
typedef __attribute__((ext_vector_type(4))) float f32x4;

// ---------------------------------------------------------------------------
// Fused conversion kernel.
//  z < NB : H -> Hb (row-major bf16, masked H-hat) and Hbt (transposed)
//  z == NB: bx<5 -> Pb[m][k]=P (zero-padded 288x288); bx in 5..9 -> Qt[n][k]=Q[k][n]
// ---------------------------------------------------------------------------
__global__ __launch_bounds__(256) void conv_all(const float* __restrict__ H,
                                                const float* __restrict__ P,
                                                const float* __restrict__ Q,
                                                __hip_bfloat16* __restrict__ Hb,
                                                __hip_bfloat16* __restrict__ Hbt,
                                                __hip_bfloat16* __restrict__ Pb,
                                                __hip_bfloat16* __restrict__ Qt) {
    const int z  = blockIdx.z;
    const int tl = threadIdx.x & 63;
    const int er = threadIdx.x >> 6;
    __shared__ float tile[64][65];

    if (z < NB) {
        const int b  = z;
        const int t0 = blockIdx.x * 64;
        const int e0 = blockIdx.y * 64;
        const float* __restrict__ Hs = H + (size_t)b * DP * NP;
        __hip_bfloat16* __restrict__ Hbb  = Hb  + (size_t)b * HROWS * 2048;
        __hip_bfloat16* __restrict__ Hbtb = Hbt + (size_t)b * TROWS * TPITCH;

#pragma unroll
        for (int r = 0; r < 16; ++r) {
            const int el = er + r * 4;        // 0..63
            const int ge = e0 + el;
            const int gt = t0 + tl;
            float v = 0.f;
            if (ge < DP && gt < NP) v = Hs[(size_t)ge * NP + gt];
            tile[el][tl] = v;
            if (ge < HROWS && gt < 2048) Hbb[(size_t)ge * 2048 + gt] = __float2bfloat16(v);
        }
        __syncthreads();
#pragma unroll
        for (int r = 0; r < 16; ++r) {
            const int ttl = er + r * 4;       // t-local
            const int gt = t0 + ttl;
            const int ge = e0 + tl;           // e-local = lane -> contiguous writes
            if (gt < TROWS && ge < TPITCH) {
                const float v = (ge < KLD) ? tile[tl][ttl] : 0.f;
                Hbtb[(size_t)gt * TPITCH + ge] = __float2bfloat16(v);
            }
        }
        return;
    }

    // z == NB: P/Q conversion (50 blocks ride along)
    const int bx = blockIdx.x;
    if (bx >= 10) return;
    const int r0 = blockIdx.y * 64;
    if (bx < 5) {
        const int c0 = bx * 64;
#pragma unroll
        for (int r = 0; r < 16; ++r) {
            const int m = r0 + er + r * 4;
            const int k = c0 + tl;
            float v = (m < DP && k < DP) ? P[m * DP + k] : 0.f;
            if (m < KLD && k < KLD) Pb[m * KLD + k] = __float2bfloat16(v);
        }
    } else {
        const int c0 = (bx - 5) * 64;
#pragma unroll
        for (int r = 0; r < 16; ++r) {
            const int k = r0 + er + r * 4;
            const int n = c0 + tl;
            float v = (k < DP && n < DP) ? Q[k * DP + n] : 0.f;
            tile[k - r0][n - c0] = v;
        }
        __syncthreads();
#pragma unroll
        for (int r = 0; r < 16; ++r) {
            const int k = r0 + tl;
            const int n = c0 + er + r * 4;
            if (n < KLD && k < KLD) Qt[n * KLD + k] = __float2bfloat16(tile[tl][n - c0]);
        }
    }
}

// ---------------------------------------------------------------------------
// G[b] = Hb[b] @ Hb[b]^T, staged 64x64 tiles, 512 threads, split-K x2.
// ---------------------------------------------------------------------------
__global__ __launch_bounds__(512, 4) void gram_staged(const __hip_bfloat16* __restrict__ Hb,
                                                      __hip_bfloat16* __restrict__ G) {
    const int b  = blockIdx.y;
    const int tm = blockIdx.x / 5;
    const int tn = blockIdx.x % 5;
    const int m0 = tm * 64, n0 = tn * 64;
    const int tid = threadIdx.x;
    const int wave = tid >> 6, lane = tid & 63;
    const int lrow = lane & 15, kq = (lane >> 4) * 8;
    const int hw = wave >> 2;            // compute half
    const int q  = wave & 3;             // quadrant
    const int mh = (q & 1) * 32, nh = (q >> 1) * 32;
    const int hs = tid >> 8;             // staging half
    const int t2 = tid & 255;
    const int sr = t2 >> 2;              // 0..63
    const int sc = (t2 & 3) * 8;         // 0,8,16,24

    __shared__ __align__(16) char smem[2 * 2 * 2 * 64 * KPAD * 2];  // 40960 B
    short* As = (short*)smem;                    // [buf][h][64][KPAD]
    short* Bs = (short*)(smem + 2 * 2 * 64 * KPAD * 2);
    float* red = (float*)smem;                   // [8][32][32] (reused after loop)

    const short* __restrict__ base = (const short*)(Hb + (size_t)b * HROWS * 2048);

    auto aoff = [&](int buf, int h, int r) { return ((buf * 2 + h) * 64 + r) * KPAD; };

    f32x4 acc[2][2] = {};

    {
        const int kb = hs * 1024;
        *(bf16x8*)&As[aoff(0, hs, sr) + sc] = *(const bf16x8*)(base + (size_t)(m0 + sr) * 2048 + kb + sc);
        *(bf16x8*)&Bs[aoff(0, hs, sr) + sc] = *(const bf16x8*)(base + (size_t)(n0 + sr) * 2048 + kb + sc);
    }
    __syncthreads();

    for (int kt = 0; kt < 32; ++kt) {
        const int cur = kt & 1, nxt = cur ^ 1;
        if (kt + 1 < 32) {
            const int kb = hs * 1024 + (kt + 1) * 32;
            *(bf16x8*)&As[aoff(nxt, hs, sr) + sc] = *(const bf16x8*)(base + (size_t)(m0 + sr) * 2048 + kb + sc);
            *(bf16x8*)&Bs[aoff(nxt, hs, sr) + sc] = *(const bf16x8*)(base + (size_t)(n0 + sr) * 2048 + kb + sc);
        }
        bf16x8 a0 = *(const bf16x8*)&As[aoff(cur, hw, mh + lrow) + kq];
        bf16x8 a1 = *(const bf16x8*)&As[aoff(cur, hw, mh + 16 + lrow) + kq];
        bf16x8 b0 = *(const bf16x8*)&Bs[aoff(cur, hw, nh + lrow) + kq];
        bf16x8 b1 = *(const bf16x8*)&Bs[aoff(cur, hw, nh + 16 + lrow) + kq];
        acc[0][0] = __builtin_amdgcn_mfma_f32_16x16x32_bf16(a0, b0, acc[0][0], 0, 0, 0);
        acc[0][1] = __builtin_amdgcn_mfma_f32_16x16x32_bf16(a0, b1, acc[0][1], 0, 0, 0);
        acc[1][0] = __builtin_amdgcn_mfma_f32_16x16x32_bf16(a1, b0, acc[1][0], 0, 0, 0);
        acc[1][1] = __builtin_amdgcn_mfma_f32_16x16x32_bf16(a1, b1, acc[1][1], 0, 0, 0);
        __syncthreads();
    }

    const int ccol  = lane & 15;
    const int crow0 = (lane >> 4) * 4;
#pragma unroll
    for (int i = 0; i < 2; ++i)
#pragma unroll
        for (int j = 0; j < 2; ++j)
#pragma unroll
            for (int r = 0; r < 4; ++r)
                red[((wave * 32) + i * 16 + crow0 + r) * 32 + j * 16 + ccol] = acc[i][j][r];
    __syncthreads();

    const int q2  = tid >> 7;
    const int t7  = tid & 127;
    const int row = t7 >> 2;
    const int c8  = (t7 & 3) * 8;
    const int gm = m0 + (q2 & 1) * 32 + row;
    const int gn = n0 + (q2 >> 1) * 32 + c8;
    if (gm < KLD && gn < KLD) {
        __hip_bfloat16 o[8];
#pragma unroll
        for (int t = 0; t < 8; ++t) {
            const float v = red[((q2 * 32) + row) * 32 + c8 + t] +
                            red[(((q2 + 4) * 32) + row) * 32 + c8 + t];
            o[t] = __float2bfloat16((gm < DP && (gn + t) < DP) ? v : 0.f);
        }
        __hip_bfloat16* __restrict__ Gb = G + (size_t)b * KLD * KLD;
        *(bf16x8*)&Gb[gm * KLD + gn] = *(const bf16x8*)o;
    }
}

// ---------------------------------------------------------------------------
// C[b][m][n] = sum_k A[m][k] * B[n][k]  (K=288, ld=288), split-K x4.
// ---------------------------------------------------------------------------
__global__ __launch_bounds__(256) void mm_sk4(const __hip_bfloat16* __restrict__ A,
                                              const __hip_bfloat16* __restrict__ B,
                                              __hip_bfloat16* __restrict__ C,
                                              int strideA, int strideB) {
    const int b  = blockIdx.y;
    const int tm = blockIdx.x / 9;
    const int tn = blockIdx.x % 9;
    const int s    = threadIdx.x >> 6;
    const int lane = threadIdx.x & 63;
    const int lrow = lane & 15;
    const int koff = (lane >> 4) * 8;
    const short* __restrict__ Ab = (const short*)(A + (size_t)b * strideA);
    const short* __restrict__ Bb = (const short*)(B + (size_t)b * strideB);
    const int m0 = tm * 32, n0 = tn * 32;

    __shared__ float red[4][32][32];

    f32x4 acc[2][2] = {};
    for (int kt = s; kt < 9; kt += 4) {
        const int k0 = kt * 32;
        bf16x8 a0 = *(const bf16x8*)(Ab + (m0 + lrow)      * KLD + k0 + koff);
        bf16x8 a1 = *(const bf16x8*)(Ab + (m0 + 16 + lrow) * KLD + k0 + koff);
        bf16x8 c0 = *(const bf16x8*)(Bb + (n0 + lrow)      * KLD + k0 + koff);
        bf16x8 c1 = *(const bf16x8*)(Bb + (n0 + 16 + lrow) * KLD + k0 + koff);
        acc[0][0] = __builtin_amdgcn_mfma_f32_16x16x32_bf16(a0, c0, acc[0][0], 0, 0, 0);
        acc[0][1] = __builtin_amdgcn_mfma_f32_16x16x32_bf16(a0, c1, acc[0][1], 0, 0, 0);
        acc[1][0] = __builtin_amdgcn_mfma_f32_16x16x32_bf16(a1, c0, acc[1][0], 0, 0, 0);
        acc[1][1] = __builtin_amdgcn_mfma_f32_16x16x32_bf16(a1, c1, acc[1][1], 0, 0, 0);
    }

    const int ccol  = lane & 15;
    const int crow0 = (lane >> 4) * 4;
#pragma unroll
    for (int i = 0; i < 2; ++i)
#pragma unroll
        for (int j = 0; j < 2; ++j)
#pragma unroll
            for (int r = 0; r < 4; ++r)
                red[s][i * 16 + crow0 + r][j * 16 + ccol] = acc[i][j][r];
    __syncthreads();

    const int row = threadIdx.x >> 3;
    const int c4  = (threadIdx.x & 7) * 4;
    float4 v0 = *(const float4*)&red[0][row][c4];
    float4 v1 = *(const float4*)&red[1][row][c4];
    float4 v2 = *(const float4*)&red[2][row][c4];
    float4 v3 = *(const float4*)&red[3][row][c4];
    float sum[4] = {v0.x + v1.x + v2.x + v3.x,
                    v0.y + v1.y + v2.y + v3.y,
                    v0.z + v1.z + v2.z + v3.z,
                    v0.w + v1.w + v2.w + v3.w};
    const int gm = m0 + row;
    const int gn = n0 + c4;
    __hip_bfloat16 o[4];
#pragma unroll
    for (int t = 0; t < 4; ++t) {
        const float v = (gm < DP && (gn + t) < DP) ? sum[t] : 0.f;
        o[t] = __float2bfloat16(v);
    }
    __hip_bfloat16* __restrict__ Cb = C + (size_t)b * KLD * KLD;
    *(bf16x4*)&Cb[gm * KLD + gn] = *(const bf16x4*)o;
}

// ---------------------------------------------------------------------------
// out[b][d][t] = H[b][d][t] + (1/n) * sum_e Kb[d][e] * Hbt[t][e]
//
// v6 = v5 main loop (double-buffered, 1 barrier/chunk, 2-deep prefetch,
// XCD swizzle) + rebuilt epilogue:
//  * whole 64x128 H tile preloaded into 32 regs/thread right after the
//    K-loop (32-deep MLP burst; latency drains under the acc dump+barrier)
//  * 2 phases of 32 d-rows (Ped [32][132] = 16.9 KB) -> 3 barriers (was 8)
//  * Ped read as float4 (col = lane*4, 16B aligned)
// ---------------------------------------------------------------------------
__global__ __launch_bounds__(256, 4) void attn_v6(const __hip_bfloat16* __restrict__ Kb,
                                                  const __hip_bfloat16* __restrict__ Hbt,
                                                  const float* __restrict__ H,
                                                  float* __restrict__ Out) {
    // XCD swizzle: 1360 blocks, 170 per XCD = 2 batches (85 = 17t x 5d each)
    const int id      = blockIdx.x;
    const int logical = (id & 7) * 170 + (id >> 3);
    const int b   = logical / 85;
    const int rem = logical % 85;
    const int t0  = (rem / 5) * 128;
    const int d0  = (rem % 5) * 64;

    const int tid = threadIdx.x;
    const int wave = tid >> 6, lane = tid & 63;
    const int lrow = lane & 15, kq = (lane >> 4) * 8;
    const int dh = (wave & 1) * 32;      // wave's d-half
    const int th = (wave >> 1) * 64;     // wave's t-half
    const int sr = tid >> 2;             // 0..63
    const int sc = (tid & 3) * 8;        // 0,8,16,24

    __shared__ __align__(16) char smem[2 * (64 + 128) * KPAD * 2];  // 30720 B
    // buffer i: A rows [0,64), B rows [64,192) at base i*192*KPAD (shorts)
    short* bufs = (short*)smem;
    float* Ped  = (float*)smem;          // [32][132] epilogue staging (16896 B)

    const short* __restrict__ Ka = (const short*)(Kb  + (size_t)b * KLD * KLD);
    const short* __restrict__ Ta = (const short*)(Hbt + (size_t)b * TROWS * TPITCH);

    int rA = d0 + sr; if (rA > KLD - 1) rA = KLD - 1;   // Kb rows 257..287 are zeros
    const short* __restrict__ gA  = Ka + (size_t)rA * KLD + sc;
    const short* __restrict__ gB0 = Ta + (size_t)(t0 + sr) * TPITCH + sc;
    const short* __restrict__ gB1 = Ta + (size_t)(t0 + 64 + sr) * TPITCH + sc;

    auto Aoff = [&](int bi, int r) { return (bi * 192 + r) * KPAD; };
    auto Boff = [&](int bi, int r) { return (bi * 192 + 64 + r) * KPAD; };

    f32x4 acc[2][4] = {};

    // prologue: chunk 0 -> buf0 (direct), chunk 1 -> regs R
    {
        bf16x8 a = *(const bf16x8*)gA;
        bf16x8 x = *(const bf16x8*)gB0;
        bf16x8 y = *(const bf16x8*)gB1;
        *(bf16x8*)&bufs[Aoff(0, sr) + sc]      = a;
        *(bf16x8*)&bufs[Boff(0, sr) + sc]      = x;
        *(bf16x8*)&bufs[Boff(0, 64 + sr) + sc] = y;
    }
    bf16x8 rA1 = *(const bf16x8*)(gA  + 32);
    bf16x8 rB0 = *(const bf16x8*)(gB0 + 32);
    bf16x8 rB1 = *(const bf16x8*)(gB1 + 32);
    __syncthreads();

#pragma unroll
    for (int kt = 0; kt < 9; ++kt) {
        const int cur = kt & 1;
        // issue loads for chunk kt+2 (consumed at iteration kt+1's ds_write)
        bf16x8 nA, nB0, nB1;
        if (kt < 7) {
            const int e = (kt + 2) * 32;
            nA  = *(const bf16x8*)(gA  + e);
            nB0 = *(const bf16x8*)(gB0 + e);
            nB1 = *(const bf16x8*)(gB1 + e);
        }
        // compute on buf[cur]
        bf16x8 af0 = *(const bf16x8*)&bufs[Aoff(cur, dh + lrow) + kq];
        bf16x8 af1 = *(const bf16x8*)&bufs[Aoff(cur, dh + 16 + lrow) + kq];
        bf16x8 bfr[4];
#pragma unroll
        for (int j = 0; j < 4; ++j)
            bfr[j] = *(const bf16x8*)&bufs[Boff(cur, th + j * 16 + lrow) + kq];
#pragma unroll
        for (int j = 0; j < 4; ++j) {
            acc[0][j] = __builtin_amdgcn_mfma_f32_16x16x32_bf16(af0, bfr[j], acc[0][j], 0, 0, 0);
            acc[1][j] = __builtin_amdgcn_mfma_f32_16x16x32_bf16(af1, bfr[j], acc[1][j], 0, 0, 0);
        }
        // write chunk kt+1 (loaded a full iteration ago) into the other buffer
        if (kt < 8) {
            *(bf16x8*)&bufs[Aoff(cur ^ 1, sr) + sc]      = rA1;
            *(bf16x8*)&bufs[Boff(cur ^ 1, sr) + sc]      = rB0;
            *(bf16x8*)&bufs[Boff(cur ^ 1, 64 + sr) + sc] = rB1;
        }
        __syncthreads();                  // ONE barrier per chunk
        if (kt < 7) { rA1 = nA; rB0 = nB0; rB1 = nB1; }
    }

    // ---------------- epilogue ----------------
    const float* __restrict__ Hs = H + (size_t)b * DP * NP;
    float* __restrict__ Ob = Out + (size_t)b * DP * NP;
    const float inv_n = 1.0f / (float)NSEQ;
    const int ccol  = lane & 15;
    const int crow0 = (lane >> 4) * 4;
    const int prow = tid >> 5;           // 0..7
    const int pcol = (tid & 31) * 4;     // 0..124

    // preload the entire 64x128 H tile: 32 regs/thread, one MLP burst
    float hreg[4][2][4];
#pragma unroll
    for (int c = 0; c < 4; ++c)
#pragma unroll
        for (int p = 0; p < 2; ++p) {
            const int gd = d0 + c * 16 + p * 8 + prow;
            if (gd < DP) {
                const size_t base = (size_t)gd * NP + t0;
#pragma unroll
                for (int cc = 0; cc < 4; ++cc) {
                    const int gt = t0 + pcol + cc;
                    if (gt < NP) hreg[c][p][cc] = Hs[base + pcol + cc];
                }
            }
        }

    // 2 phases of 32 d-rows
#pragma unroll
    for (int c2 = 0; c2 < 2; ++c2) {
        if ((wave & 1) == c2) {          // this wave's d-half == phase rows
#pragma unroll
            for (int i = 0; i < 2; ++i)
#pragma unroll
                for (int j = 0; j < 4; ++j)
#pragma unroll
                    for (int r = 0; r < 4; ++r)
                        Ped[(i * 16 + crow0 + r) * 132 + th + j * 16 + ccol] = acc[i][j][r];
        }
        __syncthreads();
#pragma unroll
        for (int c = 2 * c2; c < 2 * c2 + 2; ++c)
#pragma unroll
            for (int p = 0; p < 2; ++p) {
                const int rloc = (c & 1) * 16 + p * 8 + prow;   // 0..31
                const int gd = d0 + c * 16 + p * 8 + prow;
                if (gd < DP) {
                    const float4 pv = *(const float4*)&Ped[rloc * 132 + pcol];
                    const size_t base = (size_t)gd * NP + t0;
                    const float pva[4] = {pv.x, pv.y, pv.z, pv.w};
#pragma unroll
                    for (int cc = 0; cc < 4; ++cc) {
                        const int gt = t0 + pcol + cc;
                        if (gt < NP) Ob[base + pcol + cc] = hreg[c][p][cc] + inv_n * pva[cc];
                    }
                }
            }
        if (c2 == 0) __syncthreads();    // Ped reused by phase 1
    }
}

extern "C" void kernel_launch(void* const* d_in, const int* in_sizes, int n_in,
                              void* d_out, int out_size, void* d_ws, size_t ws_size,
                              hipStream_t stream) {
    const float* H = (const float*)d_in[0];
    const float* P = (const float*)d_in[1];
    const float* Q = (const float*)d_in[2];
    float* out = (float*)d_out;

    __hip_bfloat16* Hb  = (__hip_bfloat16*)d_ws;                   // 16*320*2048
    __hip_bfloat16* Hbt = Hb  + (size_t)NB * HROWS * 2048;         // 16*2176*320
    __hip_bfloat16* G   = Hbt + (size_t)NB * TROWS * TPITCH;       // 16*288*288
    __hip_bfloat16* Pb  = G   + (size_t)NB * KLD * KLD;            // 288*288
    __hip_bfloat16* Qt  = Pb  + (size_t)KLD * KLD;                 // 288*288
    // W and Kb alias Hb's region (Hb is dead after gram_staged)
    __hip_bfloat16* W   = Hb;
    __hip_bfloat16* Kb  = Hb + (size_t)NB * KLD * KLD;

    // fused conversions: H (z<16) + P/Q (z==16) in one launch
    conv_all<<<dim3(34, 5, NB + 1), 256, 0, stream>>>(H, P, Q, Hb, Hbt, Pb, Qt);
    // G[b] = H-hat @ H-hat^T  (staged 64x64 tiles, in-block split-K x2)
    gram_staged<<<dim3(25, NB), 512, 0, stream>>>(Hb, G);
    // W[b] = P @ G[b]   (B-frags = G rows, valid by symmetry of G)
    mm_sk4<<<dim3(81, NB), 256, 0, stream>>>(Pb, G, W, 0, KLD * KLD);
    // Kb[b] = W[b] @ Q  (B-frags = Qt rows)
    mm_sk4<<<dim3(81, NB), 256, 0, stream>>>(W, Qt, Kb, KLD * KLD, 0);
    // out = H + (Kb @ H) / n  (single launch, XCD-swizzled 1-D grid)
    attn_v6<<<dim3(17 * 5 * NB), 256, 0, stream>>>(Kb, Hbt, H, out);
}

// Round 7
// 166.555 us; speedup vs baseline: 1.3140x; 1.0422x over previous
//
#include <hip/hip_runtime.h>
#include <hip/hip_bf16.h>

#define DP     257
#define NP     2049
#define NSEQ   2048
#define NB     16
#define KLD    288         // pitch for small matrices (shorts)
#define HROWS  320         // padded rows for Hb
#define TPITCH 320         // Hbt pitch in shorts: 640 B = 5 full 128B lines
#define TROWS  2176        // padded t rows for Hbt (17*128)
#define KPAD   40          // LDS row pitch (shorts)

typedef __attribute__((ext_vector_type(8))) short bf16x8;
typedef __attribute__((ext_vector_type(4))) short bf16x4;
typedef __attribute__((ext_vector_type(4))) float f32x4;

// ---------------------------------------------------------------------------
// Fused conversion kernel.
//  z < NB : H -> Hb (row-major bf16, masked H-hat) and Hbt (transposed)
//  z == NB: bx<5 -> Pb[m][k]=P (zero-padded 288x288); bx in 5..9 -> Qt[n][k]=Q[k][n]
// ---------------------------------------------------------------------------
__global__ __launch_bounds__(256) void conv_all(const float* __restrict__ H,
                                                const float* __restrict__ P,
                                                const float* __restrict__ Q,
                                                __hip_bfloat16* __restrict__ Hb,
                                                __hip_bfloat16* __restrict__ Hbt,
                                                __hip_bfloat16* __restrict__ Pb,
                                                __hip_bfloat16* __restrict__ Qt) {
    const int z  = blockIdx.z;
    const int tl = threadIdx.x & 63;
    const int er = threadIdx.x >> 6;
    __shared__ float tile[64][65];

    if (z < NB) {
        const int b  = z;
        const int t0 = blockIdx.x * 64;
        const int e0 = blockIdx.y * 64;
        const float* __restrict__ Hs = H + (size_t)b * DP * NP;
        __hip_bfloat16* __restrict__ Hbb  = Hb  + (size_t)b * HROWS * 2048;
        __hip_bfloat16* __restrict__ Hbtb = Hbt + (size_t)b * TROWS * TPITCH;

#pragma unroll
        for (int r = 0; r < 16; ++r) {
            const int el = er + r * 4;        // 0..63
            const int ge = e0 + el;
            const int gt = t0 + tl;
            float v = 0.f;
            if (ge < DP && gt < NP) v = Hs[(size_t)ge * NP + gt];
            tile[el][tl] = v;
            if (ge < HROWS && gt < 2048) Hbb[(size_t)ge * 2048 + gt] = __float2bfloat16(v);
        }
        __syncthreads();
#pragma unroll
        for (int r = 0; r < 16; ++r) {
            const int ttl = er + r * 4;       // t-local
            const int gt = t0 + ttl;
            const int ge = e0 + tl;           // e-local = lane -> contiguous writes
            if (gt < TROWS && ge < TPITCH) {
                const float v = (ge < KLD) ? tile[tl][ttl] : 0.f;
                Hbtb[(size_t)gt * TPITCH + ge] = __float2bfloat16(v);
            }
        }
        return;
    }

    // z == NB: P/Q conversion (50 blocks ride along)
    const int bx = blockIdx.x;
    if (bx >= 10) return;
    const int r0 = blockIdx.y * 64;
    if (bx < 5) {
        const int c0 = bx * 64;
#pragma unroll
        for (int r = 0; r < 16; ++r) {
            const int m = r0 + er + r * 4;
            const int k = c0 + tl;
            float v = (m < DP && k < DP) ? P[m * DP + k] : 0.f;
            if (m < KLD && k < KLD) Pb[m * KLD + k] = __float2bfloat16(v);
        }
    } else {
        const int c0 = (bx - 5) * 64;
#pragma unroll
        for (int r = 0; r < 16; ++r) {
            const int k = r0 + er + r * 4;
            const int n = c0 + tl;
            float v = (k < DP && n < DP) ? Q[k * DP + n] : 0.f;
            tile[k - r0][n - c0] = v;
        }
        __syncthreads();
#pragma unroll
        for (int r = 0; r < 16; ++r) {
            const int k = r0 + tl;
            const int n = c0 + er + r * 4;
            if (n < KLD && k < KLD) Qt[n * KLD + k] = __float2bfloat16(tile[tl][n - c0]);
        }
    }
}

// ---------------------------------------------------------------------------
// G[b] = Hb[b] @ Hb[b]^T  -- SYMMETRIC: compute only tiles tm<=tn (15 of 25)
// and write the mirror tile transposed. 240 blocks = one residency wave on
// 256 CUs (was 400 = two sequential waves). 512 threads, split-K x2.
// ---------------------------------------------------------------------------
__global__ __launch_bounds__(512, 4) void gram_staged(const __hip_bfloat16* __restrict__ Hb,
                                                      __hip_bfloat16* __restrict__ G) {
    const int b  = blockIdx.y;
    // enumerate upper-triangle tiles: (0,0)..(0,4),(1,1)..(4,4)
    int idx = blockIdx.x, tm = 0, w = 5;
    while (idx >= w) { idx -= w; ++tm; --w; }
    const int tn = tm + idx;
    const int m0 = tm * 64, n0 = tn * 64;
    const int tid = threadIdx.x;
    const int wave = tid >> 6, lane = tid & 63;
    const int lrow = lane & 15, kq = (lane >> 4) * 8;
    const int hw = wave >> 2;            // compute half
    const int q  = wave & 3;             // quadrant
    const int mh = (q & 1) * 32, nh = (q >> 1) * 32;
    const int hs = tid >> 8;             // staging half
    const int t2 = tid & 255;
    const int sr = t2 >> 2;              // 0..63
    const int sc = (t2 & 3) * 8;         // 0,8,16,24

    __shared__ __align__(16) char smem[2 * 2 * 2 * 64 * KPAD * 2];  // 40960 B
    short* As = (short*)smem;                    // [buf][h][64][KPAD]
    short* Bs = (short*)(smem + 2 * 2 * 64 * KPAD * 2);
    float* red = (float*)smem;                   // [8][32][32] (reused after loop)

    const short* __restrict__ base = (const short*)(Hb + (size_t)b * HROWS * 2048);

    auto aoff = [&](int buf, int h, int r) { return ((buf * 2 + h) * 64 + r) * KPAD; };

    f32x4 acc[2][2] = {};

    {
        const int kb = hs * 1024;
        *(bf16x8*)&As[aoff(0, hs, sr) + sc] = *(const bf16x8*)(base + (size_t)(m0 + sr) * 2048 + kb + sc);
        *(bf16x8*)&Bs[aoff(0, hs, sr) + sc] = *(const bf16x8*)(base + (size_t)(n0 + sr) * 2048 + kb + sc);
    }
    __syncthreads();

    for (int kt = 0; kt < 32; ++kt) {
        const int cur = kt & 1, nxt = cur ^ 1;
        if (kt + 1 < 32) {
            const int kb = hs * 1024 + (kt + 1) * 32;
            *(bf16x8*)&As[aoff(nxt, hs, sr) + sc] = *(const bf16x8*)(base + (size_t)(m0 + sr) * 2048 + kb + sc);
            *(bf16x8*)&Bs[aoff(nxt, hs, sr) + sc] = *(const bf16x8*)(base + (size_t)(n0 + sr) * 2048 + kb + sc);
        }
        bf16x8 a0 = *(const bf16x8*)&As[aoff(cur, hw, mh + lrow) + kq];
        bf16x8 a1 = *(const bf16x8*)&As[aoff(cur, hw, mh + 16 + lrow) + kq];
        bf16x8 b0 = *(const bf16x8*)&Bs[aoff(cur, hw, nh + lrow) + kq];
        bf16x8 b1 = *(const bf16x8*)&Bs[aoff(cur, hw, nh + 16 + lrow) + kq];
        acc[0][0] = __builtin_amdgcn_mfma_f32_16x16x32_bf16(a0, b0, acc[0][0], 0, 0, 0);
        acc[0][1] = __builtin_amdgcn_mfma_f32_16x16x32_bf16(a0, b1, acc[0][1], 0, 0, 0);
        acc[1][0] = __builtin_amdgcn_mfma_f32_16x16x32_bf16(a1, b0, acc[1][0], 0, 0, 0);
        acc[1][1] = __builtin_amdgcn_mfma_f32_16x16x32_bf16(a1, b1, acc[1][1], 0, 0, 0);
        __syncthreads();
    }

    const int ccol  = lane & 15;
    const int crow0 = (lane >> 4) * 4;
#pragma unroll
    for (int i = 0; i < 2; ++i)
#pragma unroll
        for (int j = 0; j < 2; ++j)
#pragma unroll
            for (int r = 0; r < 4; ++r)
                red[((wave * 32) + i * 16 + crow0 + r) * 32 + j * 16 + ccol] = acc[i][j][r];
    __syncthreads();

    const int q2  = tid >> 7;
    const int t7  = tid & 127;
    const int row = t7 >> 2;
    const int c8  = (t7 & 3) * 8;
    __hip_bfloat16* __restrict__ Gb = G + (size_t)b * KLD * KLD;

    // direct tile (m0, n0)
    {
        const int gm = m0 + (q2 & 1) * 32 + row;
        const int gn = n0 + (q2 >> 1) * 32 + c8;
        if (gm < KLD && gn < KLD) {
            __hip_bfloat16 o[8];
#pragma unroll
            for (int t = 0; t < 8; ++t) {
                const float v = red[((q2 * 32) + row) * 32 + c8 + t] +
                                red[(((q2 + 4) * 32) + row) * 32 + c8 + t];
                o[t] = __float2bfloat16((gm < DP && (gn + t) < DP) ? v : 0.f);
            }
            *(bf16x8*)&Gb[gm * KLD + gn] = *(const bf16x8*)o;
        }
    }
    // mirror tile (n0, m0) = transpose (skip on the diagonal)
    if (tm != tn) {
        const int gm = n0 + (q2 & 1) * 32 + row;     // n-index as G row
        const int gn = m0 + (q2 >> 1) * 32 + c8;     // m-index as G col
        if (gm < KLD && gn < KLD) {
            const int qp = ((q2 >> 1) & 1) | ((q2 & 1) << 1);  // swap quadrant bits
            __hip_bfloat16 o[8];
#pragma unroll
            for (int t = 0; t < 8; ++t) {
                const float v = red[((qp * 32) + c8 + t) * 32 + row] +
                                red[(((qp + 4) * 32) + c8 + t) * 32 + row];
                o[t] = __float2bfloat16((gm < DP && (gn + t) < DP) ? v : 0.f);
            }
            *(bf16x8*)&Gb[gm * KLD + gn] = *(const bf16x8*)o;
        }
    }
}

// ---------------------------------------------------------------------------
// C[b][m][n] = sum_k A[m][k] * B[n][k]  (K=288, ld=288), split-K x4.
// ---------------------------------------------------------------------------
__global__ __launch_bounds__(256) void mm_sk4(const __hip_bfloat16* __restrict__ A,
                                              const __hip_bfloat16* __restrict__ B,
                                              __hip_bfloat16* __restrict__ C,
                                              int strideA, int strideB) {
    const int b  = blockIdx.y;
    const int tm = blockIdx.x / 9;
    const int tn = blockIdx.x % 9;
    const int s    = threadIdx.x >> 6;
    const int lane = threadIdx.x & 63;
    const int lrow = lane & 15;
    const int koff = (lane >> 4) * 8;
    const short* __restrict__ Ab = (const short*)(A + (size_t)b * strideA);
    const short* __restrict__ Bb = (const short*)(B + (size_t)b * strideB);
    const int m0 = tm * 32, n0 = tn * 32;

    __shared__ float red[4][32][32];

    f32x4 acc[2][2] = {};
    for (int kt = s; kt < 9; kt += 4) {
        const int k0 = kt * 32;
        bf16x8 a0 = *(const bf16x8*)(Ab + (m0 + lrow)      * KLD + k0 + koff);
        bf16x8 a1 = *(const bf16x8*)(Ab + (m0 + 16 + lrow) * KLD + k0 + koff);
        bf16x8 c0 = *(const bf16x8*)(Bb + (n0 + lrow)      * KLD + k0 + koff);
        bf16x8 c1 = *(const bf16x8*)(Bb + (n0 + 16 + lrow) * KLD + k0 + koff);
        acc[0][0] = __builtin_amdgcn_mfma_f32_16x16x32_bf16(a0, c0, acc[0][0], 0, 0, 0);
        acc[0][1] = __builtin_amdgcn_mfma_f32_16x16x32_bf16(a0, c1, acc[0][1], 0, 0, 0);
        acc[1][0] = __builtin_amdgcn_mfma_f32_16x16x32_bf16(a1, c0, acc[1][0], 0, 0, 0);
        acc[1][1] = __builtin_amdgcn_mfma_f32_16x16x32_bf16(a1, c1, acc[1][1], 0, 0, 0);
    }

    const int ccol  = lane & 15;
    const int crow0 = (lane >> 4) * 4;
#pragma unroll
    for (int i = 0; i < 2; ++i)
#pragma unroll
        for (int j = 0; j < 2; ++j)
#pragma unroll
            for (int r = 0; r < 4; ++r)
                red[s][i * 16 + crow0 + r][j * 16 + ccol] = acc[i][j][r];
    __syncthreads();

    const int row = threadIdx.x >> 3;
    const int c4  = (threadIdx.x & 7) * 4;
    float4 v0 = *(const float4*)&red[0][row][c4];
    float4 v1 = *(const float4*)&red[1][row][c4];
    float4 v2 = *(const float4*)&red[2][row][c4];
    float4 v3 = *(const float4*)&red[3][row][c4];
    float sum[4] = {v0.x + v1.x + v2.x + v3.x,
                    v0.y + v1.y + v2.y + v3.y,
                    v0.z + v1.z + v2.z + v3.z,
                    v0.w + v1.w + v2.w + v3.w};
    const int gm = m0 + row;
    const int gn = n0 + c4;
    __hip_bfloat16 o[4];
#pragma unroll
    for (int t = 0; t < 4; ++t) {
        const float v = (gm < DP && (gn + t) < DP) ? sum[t] : 0.f;
        o[t] = __float2bfloat16(v);
    }
    __hip_bfloat16* __restrict__ Cb = C + (size_t)b * KLD * KLD;
    *(bf16x4*)&Cb[gm * KLD + gn] = *(const bf16x4*)o;
}

// ---------------------------------------------------------------------------
// out[b][d][t] = H[b][d][t] + (1/n) * sum_e Kb[d][e] * Hbt[t][e]
//
// v7 = v6 with the 9th K-chunk replaced by a rank-1 update: Kb cols 257..287
// and Hbt cols 257..319 are structurally zero, so chunk 8 contributes only
// e=256. Main loop runs 8 chunks; the e=256 term is added with 12 scalar L2
// loads + FMAs on acc using the epilogue's verified C-layout mapping.
// ---------------------------------------------------------------------------
__global__ __launch_bounds__(256, 4) void attn_v7(const __hip_bfloat16* __restrict__ Kb,
                                                  const __hip_bfloat16* __restrict__ Hbt,
                                                  const float* __restrict__ H,
                                                  float* __restrict__ Out) {
    // XCD swizzle: 1360 blocks, 170 per XCD = 2 batches (85 = 17t x 5d each)
    const int id      = blockIdx.x;
    const int logical = (id & 7) * 170 + (id >> 3);
    const int b   = logical / 85;
    const int rem = logical % 85;
    const int t0  = (rem / 5) * 128;
    const int d0  = (rem % 5) * 64;

    const int tid = threadIdx.x;
    const int wave = tid >> 6, lane = tid & 63;
    const int lrow = lane & 15, kq = (lane >> 4) * 8;
    const int dh = (wave & 1) * 32;      // wave's d-half
    const int th = (wave >> 1) * 64;     // wave's t-half
    const int sr = tid >> 2;             // 0..63
    const int sc = (tid & 3) * 8;        // 0,8,16,24
    const int ccol  = lane & 15;
    const int crow0 = (lane >> 4) * 4;

    __shared__ __align__(16) char smem[2 * (64 + 128) * KPAD * 2];  // 30720 B
    // buffer i: A rows [0,64), B rows [64,192) at base i*192*KPAD (shorts)
    short* bufs = (short*)smem;
    float* Ped  = (float*)smem;          // [32][132] epilogue staging (16896 B)

    const short* __restrict__ Ka = (const short*)(Kb  + (size_t)b * KLD * KLD);
    const short* __restrict__ Ta = (const short*)(Hbt + (size_t)b * TROWS * TPITCH);

    int rA = d0 + sr; if (rA > KLD - 1) rA = KLD - 1;   // Kb rows 257..287 are zeros
    const short* __restrict__ gA  = Ka + (size_t)rA * KLD + sc;
    const short* __restrict__ gB0 = Ta + (size_t)(t0 + sr) * TPITCH + sc;
    const short* __restrict__ gB1 = Ta + (size_t)(t0 + 64 + sr) * TPITCH + sc;

    auto Aoff = [&](int bi, int r) { return (bi * 192 + r) * KPAD; };
    auto Boff = [&](int bi, int r) { return (bi * 192 + 64 + r) * KPAD; };

    f32x4 acc[2][4] = {};

    // prologue: chunk 0 -> buf0 (direct), chunk 1 -> regs R
    {
        bf16x8 a = *(const bf16x8*)gA;
        bf16x8 x = *(const bf16x8*)gB0;
        bf16x8 y = *(const bf16x8*)gB1;
        *(bf16x8*)&bufs[Aoff(0, sr) + sc]      = a;
        *(bf16x8*)&bufs[Boff(0, sr) + sc]      = x;
        *(bf16x8*)&bufs[Boff(0, 64 + sr) + sc] = y;
    }
    bf16x8 rA1 = *(const bf16x8*)(gA  + 32);
    bf16x8 rB0 = *(const bf16x8*)(gB0 + 32);
    bf16x8 rB1 = *(const bf16x8*)(gB1 + 32);
    __syncthreads();

#pragma unroll
    for (int kt = 0; kt < 8; ++kt) {
        const int cur = kt & 1;
        // issue loads for chunk kt+2 (consumed at iteration kt+1's ds_write)
        bf16x8 nA, nB0, nB1;
        if (kt < 6) {
            const int e = (kt + 2) * 32;
            nA  = *(const bf16x8*)(gA  + e);
            nB0 = *(const bf16x8*)(gB0 + e);
            nB1 = *(const bf16x8*)(gB1 + e);
        }
        // compute on buf[cur]
        bf16x8 af0 = *(const bf16x8*)&bufs[Aoff(cur, dh + lrow) + kq];
        bf16x8 af1 = *(const bf16x8*)&bufs[Aoff(cur, dh + 16 + lrow) + kq];
        bf16x8 bfr[4];
#pragma unroll
        for (int j = 0; j < 4; ++j)
            bfr[j] = *(const bf16x8*)&bufs[Boff(cur, th + j * 16 + lrow) + kq];
#pragma unroll
        for (int j = 0; j < 4; ++j) {
            acc[0][j] = __builtin_amdgcn_mfma_f32_16x16x32_bf16(af0, bfr[j], acc[0][j], 0, 0, 0);
            acc[1][j] = __builtin_amdgcn_mfma_f32_16x16x32_bf16(af1, bfr[j], acc[1][j], 0, 0, 0);
        }
        // write chunk kt+1 (loaded a full iteration ago) into the other buffer
        if (kt < 7) {
            *(bf16x8*)&bufs[Aoff(cur ^ 1, sr) + sc]      = rA1;
            *(bf16x8*)&bufs[Boff(cur ^ 1, sr) + sc]      = rB0;
            *(bf16x8*)&bufs[Boff(cur ^ 1, 64 + sr) + sc] = rB1;
        }
        __syncthreads();                  // ONE barrier per chunk
        if (kt < 6) { rA1 = nA; rB0 = nB0; rB1 = nB1; }
    }

    // rank-1 update for e = 256 (replaces chunk 8)
    {
        float bv[4];
#pragma unroll
        for (int j = 0; j < 4; ++j) {
            const int tt = t0 + th + j * 16 + ccol;
            bv[j] = __bfloat162float(*(const __hip_bfloat16*)&Ta[(size_t)tt * TPITCH + 256]);
        }
#pragma unroll
        for (int i = 0; i < 2; ++i)
#pragma unroll
            for (int r = 0; r < 4; ++r) {
                int rr = d0 + dh + i * 16 + crow0 + r;
                if (rr > KLD - 1) rr = KLD - 1;           // zero rows
                const float av = __bfloat162float(*(const __hip_bfloat16*)&Ka[(size_t)rr * KLD + 256]);
#pragma unroll
                for (int j = 0; j < 4; ++j)
                    acc[i][j][r] += av * bv[j];
            }
    }

    // ---------------- epilogue ----------------
    const float* __restrict__ Hs = H + (size_t)b * DP * NP;
    float* __restrict__ Ob = Out + (size_t)b * DP * NP;
    const float inv_n = 1.0f / (float)NSEQ;
    const int prow = tid >> 5;           // 0..7
    const int pcol = (tid & 31) * 4;     // 0..124

    // preload the entire 64x128 H tile: 32 regs/thread, one MLP burst
    float hreg[4][2][4];
#pragma unroll
    for (int c = 0; c < 4; ++c)
#pragma unroll
        for (int p = 0; p < 2; ++p) {
            const int gd = d0 + c * 16 + p * 8 + prow;
            if (gd < DP) {
                const size_t base = (size_t)gd * NP + t0;
#pragma unroll
                for (int cc = 0; cc < 4; ++cc) {
                    const int gt = t0 + pcol + cc;
                    if (gt < NP) hreg[c][p][cc] = Hs[base + pcol + cc];
                }
            }
        }

    // 2 phases of 32 d-rows
#pragma unroll
    for (int c2 = 0; c2 < 2; ++c2) {
        if ((wave & 1) == c2) {          // this wave's d-half == phase rows
#pragma unroll
            for (int i = 0; i < 2; ++i)
#pragma unroll
                for (int j = 0; j < 4; ++j)
#pragma unroll
                    for (int r = 0; r < 4; ++r)
                        Ped[(i * 16 + crow0 + r) * 132 + th + j * 16 + ccol] = acc[i][j][r];
        }
        __syncthreads();
#pragma unroll
        for (int c = 2 * c2; c < 2 * c2 + 2; ++c)
#pragma unroll
            for (int p = 0; p < 2; ++p) {
                const int rloc = (c & 1) * 16 + p * 8 + prow;   // 0..31
                const int gd = d0 + c * 16 + p * 8 + prow;
                if (gd < DP) {
                    const float4 pv = *(const float4*)&Ped[rloc * 132 + pcol];
                    const size_t base = (size_t)gd * NP + t0;
                    const float pva[4] = {pv.x, pv.y, pv.z, pv.w};
#pragma unroll
                    for (int cc = 0; cc < 4; ++cc) {
                        const int gt = t0 + pcol + cc;
                        if (gt < NP) Ob[base + pcol + cc] = hreg[c][p][cc] + inv_n * pva[cc];
                    }
                }
            }
        if (c2 == 0) __syncthreads();    // Ped reused by phase 1
    }
}

extern "C" void kernel_launch(void* const* d_in, const int* in_sizes, int n_in,
                              void* d_out, int out_size, void* d_ws, size_t ws_size,
                              hipStream_t stream) {
    const float* H = (const float*)d_in[0];
    const float* P = (const float*)d_in[1];
    const float* Q = (const float*)d_in[2];
    float* out = (float*)d_out;

    __hip_bfloat16* Hb  = (__hip_bfloat16*)d_ws;                   // 16*320*2048
    __hip_bfloat16* Hbt = Hb  + (size_t)NB * HROWS * 2048;         // 16*2176*320
    __hip_bfloat16* G   = Hbt + (size_t)NB * TROWS * TPITCH;       // 16*288*288
    __hip_bfloat16* Pb  = G   + (size_t)NB * KLD * KLD;            // 288*288
    __hip_bfloat16* Qt  = Pb  + (size_t)KLD * KLD;                 // 288*288
    // W and Kb alias Hb's region (Hb is dead after gram_staged)
    __hip_bfloat16* W   = Hb;
    __hip_bfloat16* Kb  = Hb + (size_t)NB * KLD * KLD;

    // fused conversions: H (z<16) + P/Q (z==16) in one launch
    conv_all<<<dim3(34, 5, NB + 1), 256, 0, stream>>>(H, P, Q, Hb, Hbt, Pb, Qt);
    // G[b] = H-hat @ H-hat^T  (upper-triangle tiles + mirrored writes)
    gram_staged<<<dim3(15, NB), 512, 0, stream>>>(Hb, G);
    // W[b] = P @ G[b]   (B-frags = G rows, valid by symmetry of G)
    mm_sk4<<<dim3(81, NB), 256, 0, stream>>>(Pb, G, W, 0, KLD * KLD);
    // Kb[b] = W[b] @ Q  (B-frags = Qt rows)
    mm_sk4<<<dim3(81, NB), 256, 0, stream>>>(W, Qt, Kb, KLD * KLD, 0);
    // out = H + (Kb @ H) / n  (single launch, XCD-swizzled 1-D grid)
    attn_v7<<<dim3(17 * 5 * NB), 256, 0, stream>>>(Kb, Hbt, H, out);
}